// Round 8
// baseline (244.207 us; speedup 1.0000x reference)
//
#include <hip/hip_runtime.h>
#include <hip/hip_bf16.h>

#define BSZ 4
#define SEQ 2048
#define DIM 1024

typedef __attribute__((ext_vector_type(8))) short bf16x8;
typedef __attribute__((ext_vector_type(4))) float floatx4;

__device__ __forceinline__ unsigned short f2bf(float x) {
  union { float f; unsigned int u; } v; v.f = x;
  unsigned int r = v.u + 0x7fffu + ((v.u >> 16) & 1u);
  return (unsigned short)(r >> 16);
}

// load 8 consecutive fp32, round to bf16, pack as uint4 (bf16x8 memory image)
__device__ __forceinline__ uint4 ld8f(const float* p) {
  float4 a = *(const float4*)p;
  float4 b = *(const float4*)(p + 4);
  uint4 u;
  u.x = (unsigned)f2bf(a.x) | ((unsigned)f2bf(a.y) << 16);
  u.y = (unsigned)f2bf(a.z) | ((unsigned)f2bf(a.w) << 16);
  u.z = (unsigned)f2bf(b.x) | ((unsigned)f2bf(b.y) << 16);
  u.w = (unsigned)f2bf(b.z) | ((unsigned)f2bf(b.w) << 16);
  return u;
}

template <typename T> __device__ __forceinline__ void store_c(T* p, float v);
template <> __device__ __forceinline__ void store_c<float>(float* p, float v) { *p = v; }
template <> __device__ __forceinline__ void store_c<unsigned short>(unsigned short* p, float v) { *p = f2bf(v); }

// =====================================================================
// prep: Mt = Wk x Wq^T (64 MFMA blocks, fp32-input R0-verified core),
//       cast E -> bf16 (8192 blocks, first 8 zero Rsum),
//       transpose+cast Wv -> WtV (1024 blocks).
// Mt blocks are grid-first so they overlap the BW-bound cast phase.
// =====================================================================
__global__ __launch_bounds__(256) void prep(const float* __restrict__ E,
                                            const float* __restrict__ Wq,
                                            const float* __restrict__ Wk,
                                            const float* __restrict__ Wv,
                                            unsigned short* __restrict__ Ebf,
                                            unsigned short* __restrict__ WtV,
                                            unsigned short* __restrict__ Mt,
                                            float* __restrict__ rsum) {
  __shared__ __align__(16) unsigned short As[128][72];
  __shared__ __align__(16) unsigned short Bs[128][72];
  int b = blockIdx.x;
  int tid = threadIdx.x;

  if (b < 64) {
    // ---- Mt 128x128 tile via R0-verified reg-staged core (fp32 inputs) ----
    int m0 = (b >> 3) * 128, n0 = (b & 7) * 128;
    int lane = tid & 63;
    int wid = tid >> 6;
    int wm = (wid >> 1) * 64, wn = (wid & 1) * 64;
    int lr = lane & 15, lq = lane >> 4;
    int row = tid >> 3;
    int kc = (tid & 7) * 8;

    const float* Ab = Wk + (size_t)(m0 + row) * DIM + kc;
    const float* Bb = Wq + (size_t)(n0 + row) * DIM + kc;
    size_t la = (size_t)32 * DIM;

    uint4 ra0 = ld8f(Ab);
    uint4 ra1 = ld8f(Ab + la);
    uint4 ra2 = ld8f(Ab + 2 * la);
    uint4 ra3 = ld8f(Ab + 3 * la);
    uint4 rb0 = ld8f(Bb);
    uint4 rb1 = ld8f(Bb + la);
    uint4 rb2 = ld8f(Bb + 2 * la);
    uint4 rb3 = ld8f(Bb + 3 * la);

    floatx4 acc[4][4] = {};

    for (int k0 = 0; k0 < DIM; k0 += 64) {
      __syncthreads();
      *(uint4*)&As[row][kc]      = ra0;
      *(uint4*)&As[row + 32][kc] = ra1;
      *(uint4*)&As[row + 64][kc] = ra2;
      *(uint4*)&As[row + 96][kc] = ra3;
      *(uint4*)&Bs[row][kc]      = rb0;
      *(uint4*)&Bs[row + 32][kc] = rb1;
      *(uint4*)&Bs[row + 64][kc] = rb2;
      *(uint4*)&Bs[row + 96][kc] = rb3;
      if (k0 + 64 < DIM) {
        const float* An = Ab + k0 + 64;
        const float* Bn = Bb + k0 + 64;
        ra0 = ld8f(An);
        ra1 = ld8f(An + la);
        ra2 = ld8f(An + 2 * la);
        ra3 = ld8f(An + 3 * la);
        rb0 = ld8f(Bn);
        rb1 = ld8f(Bn + la);
        rb2 = ld8f(Bn + 2 * la);
        rb3 = ld8f(Bn + 3 * la);
      }
      __syncthreads();
#pragma unroll
      for (int kk = 0; kk < 64; kk += 32) {
        bf16x8 af[4], bfr[4];
        int kl = kk + lq * 8;
#pragma unroll
        for (int i = 0; i < 4; i++) af[i] = *(const bf16x8*)&As[wm + i * 16 + lr][kl];
#pragma unroll
        for (int j = 0; j < 4; j++) bfr[j] = *(const bf16x8*)&Bs[wn + j * 16 + lr][kl];
#pragma unroll
        for (int i = 0; i < 4; i++)
#pragma unroll
          for (int j = 0; j < 4; j++)
            acc[i][j] = __builtin_amdgcn_mfma_f32_16x16x32_bf16(af[i], bfr[j], acc[i][j], 0, 0, 0);
      }
    }
#pragma unroll
    for (int i = 0; i < 4; i++) {
      int rbase = m0 + wm + i * 16 + lq * 4;
#pragma unroll
      for (int j = 0; j < 4; j++) {
        int col = n0 + wn + j * 16 + lr;
#pragma unroll
        for (int r = 0; r < 4; r++)
          Mt[(size_t)(rbase + r) * DIM + col] = f2bf(acc[i][j][r]);
      }
    }
  } else if (b < 8256) {
    // ---- cast E (R6-proven) ----
    int base = b - 64;
    if (base < 8) {
      int j = base * 1024 + tid * 4;
      *(float4*)(rsum + j) = make_float4(0.f, 0.f, 0.f, 0.f);
    }
    int i = (base * 256 + tid) * 4;
    float4 v = *(const float4*)(E + i);
    ushort4 o;
    o.x = f2bf(v.x); o.y = f2bf(v.y); o.z = f2bf(v.z); o.w = f2bf(v.w);
    *(ushort4*)(Ebf + i) = o;
  } else {
    // ---- transpose+cast Wv (R6-proven), tile overlaid on As ----
    float* tileF = (float*)As;          // [32][33]
    int rb = b - 8256;                  // [0,1024)
    int bx = rb & 31, by = rb >> 5;
    int n0 = bx * 32, k0 = by * 32;
    int tx = tid & 31, ty = tid >> 5;   // 32 x 8
    for (int r = ty; r < 32; r += 8)
      tileF[r * 33 + tx] = Wv[(size_t)(k0 + r) * DIM + n0 + tx];
    __syncthreads();
    for (int r = ty; r < 32; r += 8)
      WtV[(size_t)(n0 + r) * DIM + k0 + tx] = f2bf(tileF[tx * 33 + r]);
  }
}

__device__ __forceinline__ void gload16(const unsigned short* g, unsigned short* l) {
  __builtin_amdgcn_global_load_lds(
      (const __attribute__((address_space(1))) unsigned int*)g,
      (__attribute__((address_space(3))) unsigned int*)l, 16, 0, 0);
}

// ---------------- R2-proven ring-4 core (128x256 tiles, 512 threads) — FROZEN ----------------
#define NT_PROJ 32  // K=1024 / BK=32

template <int BMt>
__device__ __forceinline__ void proj_core(
    const unsigned short* __restrict__ A,
    const unsigned short* __restrict__ Bm,
    unsigned short* __restrict__ C, int ldc, int m0, int n0,
    unsigned short* sAr, unsigned short* sBr) {
  constexpr int LPA = BMt / 128;
  constexpr int LPT = LPA + 2;
  constexpr int FR  = BMt / 32;
  constexpr int TA  = BMt * 32;
  constexpr int TB  = 256 * 32;

  const int tid = threadIdx.x;
  const int lane = tid & 63;
  const int wid = tid >> 6;
  const int wm = (wid >> 2) * (BMt / 2);
  const int wn = (wid & 3) * 64;
  const int lr = lane & 15, lq = lane >> 4;

  const int srow = tid >> 2;
  const int schunk = (tid & 3) ^ ((tid >> 3) & 3);
  const unsigned short* gA = A + (size_t)(m0 + srow) * DIM + schunk * 8;
  const unsigned short* gB = Bm + (size_t)(n0 + srow) * DIM + schunk * 8;
  unsigned short* lA = sAr + 16 * 32 * wid;
  unsigned short* lB = sBr + 16 * 32 * wid;
  const size_t swG = (size_t)128 * DIM;

#define STAGE_A(T) do { int rb_ = (T) & 3; \
    gload16(gA + (size_t)(T) * 32, lA + rb_ * TA); \
    if constexpr (LPA == 2) gload16(gA + (size_t)(T) * 32 + swG, lA + rb_ * TA + 4096); } while (0)
#define STAGE_B(T) do { int rb_ = (T) & 3; \
    gload16(gB + (size_t)(T) * 32,       lB + rb_ * TB); \
    gload16(gB + (size_t)(T) * 32 + swG, lB + rb_ * TB + 4096); } while (0)
#define ARD(rb_, rowv) (*(const bf16x8*)&sAr[(rb_) * TA + (rowv) * 32 + (lq ^ (((rowv) >> 1) & 3)) * 8])
#define BRD(rb_, rowv) (*(const bf16x8*)&sBr[(rb_) * TB + (rowv) * 32 + (lq ^ (((rowv) >> 1) & 3)) * 8])

  floatx4 acc[FR][4] = {};

  STAGE_A(0); STAGE_B(0);
  STAGE_A(1); STAGE_B(1);
  STAGE_A(2); STAGE_B(2);
  if constexpr (LPT == 4) asm volatile("s_waitcnt vmcnt(8)" ::: "memory");
  else                    asm volatile("s_waitcnt vmcnt(6)" ::: "memory");
  __builtin_amdgcn_s_barrier();

#pragma unroll 4
  for (int T = 0; T < NT_PROJ; ++T) {
    const int rb = T & 3;
    bf16x8 af[4], bfr[4];
#pragma unroll
    for (int j = 0; j < 4; ++j) bfr[j] = BRD(rb, wn + j * 16 + lr);
#pragma unroll
    for (int i = 0; i < 4; ++i) af[i] = ARD(rb, wm + i * 16 + lr);
    if (T + 3 < NT_PROJ) {
      STAGE_A(T + 3);
      if constexpr (BMt == 128) STAGE_B(T + 3);
    }
    __builtin_amdgcn_s_barrier();
    __builtin_amdgcn_s_setprio(1);
#pragma unroll
    for (int i = 0; i < 4; ++i)
#pragma unroll
      for (int j = 0; j < 4; ++j)
        acc[i][j] = __builtin_amdgcn_mfma_f32_16x16x32_bf16(af[i], bfr[j], acc[i][j], 0, 0, 0);
    __builtin_amdgcn_s_setprio(0);
    if constexpr (BMt == 256) {
      __builtin_amdgcn_s_barrier();
#pragma unroll
      for (int i = 0; i < 4; ++i) af[i] = ARD(rb, wm + 64 + i * 16 + lr);
      if (T + 3 < NT_PROJ) STAGE_B(T + 3);
      __builtin_amdgcn_s_barrier();
      __builtin_amdgcn_s_setprio(1);
#pragma unroll
      for (int i = 0; i < 4; ++i)
#pragma unroll
        for (int j = 0; j < 4; ++j)
          acc[4 + i][j] = __builtin_amdgcn_mfma_f32_16x16x32_bf16(af[i], bfr[j], acc[4 + i][j], 0, 0, 0);
      __builtin_amdgcn_s_setprio(0);
    }
    if (T < NT_PROJ - 3) {
      if constexpr (LPT == 4) asm volatile("s_waitcnt vmcnt(8)" ::: "memory");
      else                    asm volatile("s_waitcnt vmcnt(6)" ::: "memory");
    } else if (T == NT_PROJ - 3) {
      if constexpr (LPT == 4) asm volatile("s_waitcnt vmcnt(4)" ::: "memory");
      else                    asm volatile("s_waitcnt vmcnt(3)" ::: "memory");
    } else if (T == NT_PROJ - 2) {
      asm volatile("s_waitcnt vmcnt(0)" ::: "memory");
    }
    __builtin_amdgcn_s_barrier();
  }
#undef STAGE_A
#undef STAGE_B
#undef ARD
#undef BRD

#pragma unroll
  for (int i = 0; i < FR; ++i) {
    int rbase = m0 + wm + i * 16 + lq * 4;
#pragma unroll
    for (int j = 0; j < 4; ++j) {
      int col = n0 + wn + j * 16 + lr;
#pragma unroll
      for (int r = 0; r < 4; ++r)
        C[(size_t)(rbase + r) * ldc + col] = f2bf(acc[i][j][r]);
    }
  }
}

// ---------------- bulk: Vt (256 blk) + EM (256 blk) = exactly 2 rounds ----------------
__global__ __launch_bounds__(512, 2) void bulk(
    const unsigned short* __restrict__ Ebf,
    const unsigned short* __restrict__ WtV,
    const unsigned short* __restrict__ Mt,
    unsigned short* __restrict__ Vt,
    unsigned short* __restrict__ EM) {
  __shared__ __align__(16) unsigned short sA[16384];  // 32 KiB (ring 4 x 128x32)
  __shared__ __align__(16) unsigned short sB[32768];  // 64 KiB (ring 4 x 256x32)
  int x = blockIdx.x;
  if (x < 256) {
    // Vt = WtV x Ebf^T : [1024][8192], 128x256 tiles (8x32)
    proj_core<128>(WtV, Ebf, Vt, BSZ * SEQ, (x >> 5) * 128, (x & 31) * 256, sA, sB);
  } else {
    // EM = Ebf x Mt^T : [8192][1024], 128x256 tiles (64x4)
    x -= 256;
    proj_core<128>(Ebf, Mt, EM, DIM, (x >> 2) * 128, (x & 3) * 256, sA, sB);
  }
}

// =====================================================================
// scores / PV on the R2-proven ring-4 core (R5/R6-verified), 256-thread 128x128.
// MODE 1: scores = EM x Ebf^T -> exp numerator + rowsum atomics (tri grid).
// MODE 2: PV with causal Keff, complementary z-pairing (R6-verified).
// =====================================================================
template <typename OutT, int MODE>
__global__ __launch_bounds__(256, 2) void gemm_ring(
    const unsigned short* __restrict__ A, int lda, long long strideA,
    const unsigned short* __restrict__ B, int ldb, long long strideB,
    OutT* __restrict__ C, int ldc, long long strideC,
    int Kdim, float scale, float* __restrict__ rowsum) {
  int m0, n0;
  if constexpr (MODE == 1) {
    int t = blockIdx.x;           // packed lower-triangle decode
    int mt = 0;
    while (((mt + 1) * (mt + 2)) / 2 <= t) mt++;
    int nt = t - (mt * (mt + 1)) / 2;
    m0 = mt * 128; n0 = nt * 128;
  } else {
    int yy = ((blockIdx.z >> 1) & 1) ? blockIdx.y : (gridDim.y - 1 - blockIdx.y);
    m0 = yy * 128;
    n0 = blockIdx.x * 128;
  }
  const int Keff = (MODE == 2) ? min(Kdim, m0 + 128) : Kdim;
  const int NT = Keff >> 5;
  A += (long long)blockIdx.z * strideA;
  B += (long long)blockIdx.z * strideB;
  C += (long long)blockIdx.z * strideC;
  rowsum += (size_t)blockIdx.z * SEQ;

  __shared__ __align__(16) unsigned short sA[4 * 4096];  // 32 KiB
  __shared__ __align__(16) unsigned short sB[4 * 4096];  // 32 KiB

  const int tid = threadIdx.x;
  const int lane = tid & 63;
  const int wid = tid >> 6;
  const int wm = (wid >> 1) * 64, wn = (wid & 1) * 64;
  const int lr = lane & 15, lq = lane >> 4;

  const int schunk = (tid & 3) ^ ((tid >> 3) & 3);
  const unsigned short* gA = A + (size_t)(m0 + (tid >> 2)) * lda + schunk * 8;
  const unsigned short* gB = B + (size_t)(n0 + (tid >> 2)) * ldb + schunk * 8;
  unsigned short* lA = sA + wid * 512;
  unsigned short* lB = sB + wid * 512;
  const size_t sGA = (size_t)64 * lda, sGB = (size_t)64 * ldb;

#define RSTAGE(T) do { int rb_ = (T) & 3; \
    gload16(gA + (size_t)(T) * 32,       lA + rb_ * 4096); \
    gload16(gA + (size_t)(T) * 32 + sGA, lA + rb_ * 4096 + 2048); \
    gload16(gB + (size_t)(T) * 32,       lB + rb_ * 4096); \
    gload16(gB + (size_t)(T) * 32 + sGB, lB + rb_ * 4096 + 2048); } while (0)
#define RARD(rb_, rowv) (*(const bf16x8*)&sA[(rb_) * 4096 + (rowv) * 32 + (lq ^ (((rowv) >> 1) & 3)) * 8])
#define RBRD(rb_, rowv) (*(const bf16x8*)&sB[(rb_) * 4096 + (rowv) * 32 + (lq ^ (((rowv) >> 1) & 3)) * 8])

  floatx4 acc[4][4] = {};

  RSTAGE(0); RSTAGE(1); RSTAGE(2);
  asm volatile("s_waitcnt vmcnt(8)" ::: "memory");
  __builtin_amdgcn_s_barrier();

  for (int T = 0; T < NT; ++T) {
    const int rb = T & 3;
    bf16x8 af[4], bfr[4];
#pragma unroll
    for (int j = 0; j < 4; ++j) bfr[j] = RBRD(rb, wn + j * 16 + lr);
#pragma unroll
    for (int i = 0; i < 4; ++i) af[i] = RARD(rb, wm + i * 16 + lr);
    if (T + 3 < NT) RSTAGE(T + 3);
    __builtin_amdgcn_s_barrier();
    __builtin_amdgcn_s_setprio(1);
#pragma unroll
    for (int i = 0; i < 4; ++i)
#pragma unroll
      for (int j = 0; j < 4; ++j)
        acc[i][j] = __builtin_amdgcn_mfma_f32_16x16x32_bf16(af[i], bfr[j], acc[i][j], 0, 0, 0);
    __builtin_amdgcn_s_setprio(0);
    if (T < NT - 3)       asm volatile("s_waitcnt vmcnt(8)" ::: "memory");
    else if (T == NT - 3) asm volatile("s_waitcnt vmcnt(4)" ::: "memory");
    else if (T == NT - 2) asm volatile("s_waitcnt vmcnt(0)" ::: "memory");
    __builtin_amdgcn_s_barrier();
  }
#undef RSTAGE
#undef RARD
#undef RBRD

  if constexpr (MODE == 1) {
#pragma unroll
    for (int i = 0; i < 4; i++) {
      int rbase = m0 + wm + i * 16 + lq * 4;
      float s0 = 0.f, s1 = 0.f, s2 = 0.f, s3 = 0.f;
#pragma unroll
      for (int j = 0; j < 4; j++) {
        int col = n0 + wn + j * 16 + lr;
        float e0 = (col <= rbase + 0) ? __expf(acc[i][j][0] * scale) : 0.0f;
        float e1 = (col <= rbase + 1) ? __expf(acc[i][j][1] * scale) : 0.0f;
        float e2 = (col <= rbase + 2) ? __expf(acc[i][j][2] * scale) : 0.0f;
        float e3 = (col <= rbase + 3) ? __expf(acc[i][j][3] * scale) : 0.0f;
        store_c(&C[(size_t)(rbase + 0) * ldc + col], e0);
        store_c(&C[(size_t)(rbase + 1) * ldc + col], e1);
        store_c(&C[(size_t)(rbase + 2) * ldc + col], e2);
        store_c(&C[(size_t)(rbase + 3) * ldc + col], e3);
        s0 += e0; s1 += e1; s2 += e2; s3 += e3;
      }
#pragma unroll
      for (int m = 1; m < 16; m <<= 1) {
        s0 += __shfl_xor(s0, m, 64);
        s1 += __shfl_xor(s1, m, 64);
        s2 += __shfl_xor(s2, m, 64);
        s3 += __shfl_xor(s3, m, 64);
      }
      if (lr == 0) {
        atomicAdd(&rowsum[rbase + 0], s0);
        atomicAdd(&rowsum[rbase + 1], s1);
        atomicAdd(&rowsum[rbase + 2], s2);
        atomicAdd(&rowsum[rbase + 3], s3);
      }
    }
  } else {
#pragma unroll
    for (int i = 0; i < 4; i++) {
      int rbase = m0 + wm + i * 16 + lq * 4;
      float i0 = 1.0f / rowsum[rbase + 0];
      float i1 = 1.0f / rowsum[rbase + 1];
      float i2 = 1.0f / rowsum[rbase + 2];
      float i3 = 1.0f / rowsum[rbase + 3];
#pragma unroll
      for (int j = 0; j < 4; j++) {
        int col = n0 + wn + j * 16 + lr;
        store_c(&C[(size_t)(rbase + 0) * ldc + col], acc[i][j][0] * i0);
        store_c(&C[(size_t)(rbase + 1) * ldc + col], acc[i][j][1] * i1);
        store_c(&C[(size_t)(rbase + 2) * ldc + col], acc[i][j][2] * i2);
        store_c(&C[(size_t)(rbase + 3) * ldc + col], acc[i][j][3] * i3);
      }
    }
  }
}

extern "C" void kernel_launch(void* const* d_in, const int* in_sizes, int n_in,
                              void* d_out, int out_size, void* d_ws, size_t ws_size,
                              hipStream_t stream) {
  const float* E  = (const float*)d_in[0];
  const float* Wq = (const float*)d_in[1];
  const float* Wk = (const float*)d_in[2];
  const float* Wv = (const float*)d_in[3];
  float* out = (float*)d_out;

  char* ws = (char*)d_ws;
  size_t off = 0;
  auto alloc = [&](size_t bytes) {
    void* p = ws + off;
    off += (bytes + 255) & ~(size_t)255;
    return p;
  };
  const size_t M_ALL = (size_t)BSZ * SEQ;
  unsigned short* Ebf  = (unsigned short*)alloc(M_ALL * DIM * 2);
  unsigned short* WtV  = (unsigned short*)alloc((size_t)DIM * DIM * 2);
  unsigned short* Mt   = (unsigned short*)alloc((size_t)DIM * DIM * 2);
  unsigned short* EM   = (unsigned short*)alloc(M_ALL * DIM * 2);
  unsigned short* Vt   = (unsigned short*)alloc((size_t)DIM * M_ALL * 2);
  unsigned short* ExpS = (unsigned short*)alloc((size_t)BSZ * SEQ * SEQ * 2);
  float*          Rsum = (float*)alloc((size_t)BSZ * SEQ * 4);

  // Mt (64 MFMA blocks, grid-first) + cast E + Wv transpose + Rsum zero
  prep<<<dim3(9280), dim3(256), 0, stream>>>(E, Wq, Wk, Wv, Ebf, WtV, Mt, Rsum);

  // Vt (256 blk) + EM (256 blk): exactly 2 clean rounds at 1 block/CU
  bulk<<<dim3(512), dim3(512), 0, stream>>>(Ebf, WtV, Mt, Vt, EM);

  // scores = EM x Ebf^T -> exp numerators (bf16) + rowsum atomics; tri grid
  gemm_ring<unsigned short, 1><<<dim3(136, 1, BSZ), dim3(256), 0, stream>>>(
      EM, DIM, (long long)SEQ * DIM,
      Ebf, DIM, (long long)SEQ * DIM,
      ExpS, SEQ, (long long)SEQ * SEQ,
      DIM, 0.03125f /* 1/sqrt(1024) */, Rsum);

  // PV: out[q][d] = (sum_k expS[q][k] * Vt[d][k]) / rowsum[q]
  gemm_ring<float, 2><<<dim3(8, 16, BSZ), dim3(256), 0, stream>>>(
      ExpS, SEQ, (long long)SEQ * SEQ,
      Vt, (int)M_ALL, (long long)SEQ,
      out, DIM, (long long)SEQ * DIM,
      SEQ, 1.0f, Rsum);
}

// Round 9
// 233.562 us; speedup vs baseline: 1.0456x; 1.0456x over previous
//
#include <hip/hip_runtime.h>
#include <hip/hip_bf16.h>

#define BSZ 4
#define SEQ 2048
#define DIM 1024

typedef __attribute__((ext_vector_type(8))) short bf16x8;
typedef __attribute__((ext_vector_type(4))) float floatx4;

__device__ __forceinline__ unsigned short f2bf(float x) {
  union { float f; unsigned int u; } v; v.f = x;
  unsigned int r = v.u + 0x7fffu + ((v.u >> 16) & 1u);
  return (unsigned short)(r >> 16);
}

template <typename T> __device__ __forceinline__ void store_c(T* p, float v);
template <> __device__ __forceinline__ void store_c<float>(float* p, float v) { *p = v; }
template <> __device__ __forceinline__ void store_c<unsigned short>(unsigned short* p, float v) { *p = f2bf(v); }

// ---------------- merged prep (R6-verified): cast E + zero Rsum + transpose weights ----------------
__global__ __launch_bounds__(256) void prep(const float* __restrict__ E,
                                            const float* __restrict__ Wq,
                                            const float* __restrict__ Wk,
                                            const float* __restrict__ Wv,
                                            unsigned short* __restrict__ Ebf,
                                            unsigned short* __restrict__ WtQK,
                                            unsigned short* __restrict__ WtV,
                                            float* __restrict__ rsum, int n) {
  __shared__ float tile[32][33];
  int b = blockIdx.x;
  int tid = threadIdx.x;
  if (b < 8192) {
    if (b < 8) {
      int j = b * 1024 + tid * 4;
      *(float4*)(rsum + j) = make_float4(0.f, 0.f, 0.f, 0.f);
    }
    int i = (b * 256 + tid) * 4;
    if (i >= n) return;
    float4 v = *(const float4*)(E + i);
    ushort4 o;
    o.x = f2bf(v.x); o.y = f2bf(v.y); o.z = f2bf(v.z); o.w = f2bf(v.w);
    *(ushort4*)(Ebf + i) = o;
  } else {
    b -= 8192;
    int z = b >> 10;             // 0..2
    int rb = b & 1023;
    int bx = rb & 31, by = rb >> 5;
    const float* W = (z == 0) ? Wq : (z == 1) ? Wk : Wv;
    unsigned short* dst = (z == 2) ? WtV : WtQK;
    int row_off = (z == 1) ? 1024 : 0;
    int n0 = bx * 32, k0 = by * 32;
    int tx = tid & 31, ty = tid >> 5;   // 32 x 8
    for (int r = ty; r < 32; r += 8)
      tile[r][tx] = W[(size_t)(k0 + r) * DIM + n0 + tx];
    __syncthreads();
    for (int r = ty; r < 32; r += 8)
      dst[(size_t)(row_off + n0 + r) * DIM + k0 + tx] = f2bf(tile[tx][r]);
  }
}

__device__ __forceinline__ void gload16(const unsigned short* g, unsigned short* l) {
  __builtin_amdgcn_global_load_lds(
      (const __attribute__((address_space(1))) unsigned int*)g,
      (__attribute__((address_space(3))) unsigned int*)l, 16, 0, 0);
}

// =====================================================================
// 8-phase 256x256 GEMM core (QK path) — R4-verified, FROZEN.
// =====================================================================
__device__ __forceinline__ void proj8ph(
    const unsigned short* __restrict__ A,
    const unsigned short* __restrict__ Bm,
    unsigned short* __restrict__ C, int ldc, int m0, int n0,
    unsigned short* sA, unsigned short* sB) {
  const int tid = threadIdx.x;
  const int lane = tid & 63;
  const int wid = tid >> 6;            // 0..7
  const int wm = (wid >> 2) * 128;     // 0 / 128
  const int wn = (wid & 3) * 64;       // 0/64/128/192
  const int lr = lane & 15, lq = lane >> 4;

  unsigned short* aB = sA + (wm >> 7) * 8192 + lr * 64;
  unsigned short* bB = sB + (wn >> 7) * 8192 + ((wn & 64) + lr) * 64;
  const int sw0 = (lq ^ (lr & 7)) * 8;
  const int sw1 = ((4 + lq) ^ (lr & 7)) * 8;

  const int schunk = (tid & 7) ^ ((tid >> 3) & 7);
  const unsigned short* gA = A + (size_t)(m0 + (tid >> 3)) * DIM + schunk * 8;
  const unsigned short* gB = Bm + (size_t)(n0 + (tid >> 3)) * DIM + schunk * 8;
  unsigned short* lA = sA + wid * 512;
  unsigned short* lB = sB + wid * 512;

#define STG_A(buf, T, half) do { \
    gload16(gA + (size_t)((half) * 128) * DIM + (T) * 64,      lA + (buf) * 16384 + (half) * 8192); \
    gload16(gA + (size_t)((half) * 128 + 64) * DIM + (T) * 64, lA + (buf) * 16384 + (half) * 8192 + 4096); } while (0)
#define STG_B(buf, T, half) do { \
    gload16(gB + (size_t)((half) * 128) * DIM + (T) * 64,      lB + (buf) * 16384 + (half) * 8192); \
    gload16(gB + (size_t)((half) * 128 + 64) * DIM + (T) * 64, lB + (buf) * 16384 + (half) * 8192 + 4096); } while (0)
#define RD_A(buf, qr) do { _Pragma("unroll") for (int i_ = 0; i_ < 4; ++i_) { \
    af[i_][0] = *(const bf16x8*)(aB + (buf) * 16384 + ((qr) * 64 + i_ * 16) * 64 + sw0); \
    af[i_][1] = *(const bf16x8*)(aB + (buf) * 16384 + ((qr) * 64 + i_ * 16) * 64 + sw1); } } while (0)
#define RD_B(buf, qc) do { _Pragma("unroll") for (int j_ = 0; j_ < 2; ++j_) { \
    bq[qc][j_][0] = *(const bf16x8*)(bB + (buf) * 16384 + ((qc) * 32 + j_ * 16) * 64 + sw0); \
    bq[qc][j_][1] = *(const bf16x8*)(bB + (buf) * 16384 + ((qc) * 32 + j_ * 16) * 64 + sw1); } } while (0)
#define MM(qr, qc) do { __builtin_amdgcn_s_setprio(1); \
    _Pragma("unroll") for (int i_ = 0; i_ < 4; ++i_) \
    _Pragma("unroll") for (int jj_ = 0; jj_ < 2; ++jj_) { \
      acc[(qr)*4+i_][(qc)*2+jj_] = __builtin_amdgcn_mfma_f32_16x16x32_bf16(af[i_][0], bq[qc][jj_][0], acc[(qr)*4+i_][(qc)*2+jj_], 0, 0, 0); \
      acc[(qr)*4+i_][(qc)*2+jj_] = __builtin_amdgcn_mfma_f32_16x16x32_bf16(af[i_][1], bq[qc][jj_][1], acc[(qr)*4+i_][(qc)*2+jj_], 0, 0, 0); } \
    __builtin_amdgcn_s_setprio(0); } while (0)
#define BAR __builtin_amdgcn_s_barrier()
#define LGKM0 do { asm volatile("s_waitcnt lgkmcnt(0)" ::: "memory"); __builtin_amdgcn_sched_barrier(0); } while (0)
#define VM4 asm volatile("s_waitcnt vmcnt(4)" ::: "memory")
#define VM0 asm volatile("s_waitcnt vmcnt(0)" ::: "memory")

  floatx4 acc[8][4] = {};
  bf16x8 af[4][2], bq[2][2][2];

  STG_B(0, 0, 0); STG_B(0, 0, 1);
  STG_A(0, 0, 0); STG_A(0, 0, 1);
  STG_B(1, 1, 0); STG_B(1, 1, 1);
  VM4;
  BAR;

#pragma unroll 1
  for (int j = 0; j < 8; ++j) {
    const int t0 = 2 * j, t1 = 2 * j + 1;
    const bool st = (j < 7);
    RD_A(0, 0); RD_B(0, 0);
    STG_A(1, t1, 0);
    BAR; LGKM0; MM(0, 0); BAR;

    RD_B(0, 1);
    STG_A(1, t1, 1);
    BAR; LGKM0; MM(0, 1); BAR;

    RD_A(0, 1);
    if (st) STG_B(0, t0 + 2, 0);
    BAR; LGKM0; MM(1, 0); BAR;

    if (st) STG_B(0, t0 + 2, 1);
    BAR; MM(1, 1);
    if (st) { VM4; } else { VM0; }
    BAR;

    RD_A(1, 0); RD_B(1, 0);
    if (st) STG_A(0, t0 + 2, 0);
    BAR; LGKM0; MM(0, 0); BAR;

    RD_B(1, 1);
    if (st) STG_A(0, t0 + 2, 1);
    BAR; LGKM0; MM(0, 1); BAR;

    RD_A(1, 1);
    if (st) STG_B(1, t1 + 2, 0);
    BAR; LGKM0; MM(1, 0); BAR;

    if (st) STG_B(1, t1 + 2, 1);
    BAR; MM(1, 1);
    if (st) { VM4; }
    BAR;
  }
#undef STG_A
#undef STG_B
#undef RD_A
#undef RD_B
#undef MM
#undef BAR
#undef LGKM0
#undef VM4
#undef VM0

#pragma unroll
  for (int i = 0; i < 8; ++i) {
    int rbase = m0 + wm + i * 16 + lq * 4;
#pragma unroll
    for (int jc = 0; jc < 4; ++jc) {
      int col = n0 + wn + jc * 16 + lr;
#pragma unroll
      for (int r = 0; r < 4; ++r)
        C[(size_t)(rbase + r) * ldc + col] = f2bf(acc[i][jc][r]);
    }
  }
}

// ---------------- R2-proven ring-4 core — FROZEN schedule, now parameterized by lda/ldb
// and a MODE template (0 = plain bf16 store; 1 = exp/mask/rowsum epilogue). ----------------
#define NT_PROJ 32  // K=1024 / BK=32

template <int BMt, int MODE = 0>
__device__ __forceinline__ void proj_core(
    const unsigned short* __restrict__ A, int lda,
    const unsigned short* __restrict__ Bm, int ldb,
    unsigned short* __restrict__ C, int ldc, int m0, int n0,
    unsigned short* sAr, unsigned short* sBr,
    float scale = 0.f, float* __restrict__ rowsum = nullptr) {
  constexpr int LPA = BMt / 128;
  constexpr int LPT = LPA + 2;
  constexpr int FR  = BMt / 32;
  constexpr int TA  = BMt * 32;
  constexpr int TB  = 256 * 32;

  const int tid = threadIdx.x;
  const int lane = tid & 63;
  const int wid = tid >> 6;
  const int wm = (wid >> 2) * (BMt / 2);
  const int wn = (wid & 3) * 64;
  const int lr = lane & 15, lq = lane >> 4;

  const int srow = tid >> 2;
  const int schunk = (tid & 3) ^ ((tid >> 3) & 3);
  const unsigned short* gA = A + (size_t)(m0 + srow) * lda + schunk * 8;
  const unsigned short* gB = Bm + (size_t)(n0 + srow) * ldb + schunk * 8;
  unsigned short* lA = sAr + 16 * 32 * wid;
  unsigned short* lB = sBr + 16 * 32 * wid;
  const size_t swGA = (size_t)128 * lda;
  const size_t swGB = (size_t)128 * ldb;

#define STAGE_A(T) do { int rb_ = (T) & 3; \
    gload16(gA + (size_t)(T) * 32, lA + rb_ * TA); \
    if constexpr (LPA == 2) gload16(gA + (size_t)(T) * 32 + swGA, lA + rb_ * TA + 4096); } while (0)
#define STAGE_B(T) do { int rb_ = (T) & 3; \
    gload16(gB + (size_t)(T) * 32,        lB + rb_ * TB); \
    gload16(gB + (size_t)(T) * 32 + swGB, lB + rb_ * TB + 4096); } while (0)
#define ARD(rb_, rowv) (*(const bf16x8*)&sAr[(rb_) * TA + (rowv) * 32 + (lq ^ (((rowv) >> 1) & 3)) * 8])
#define BRD(rb_, rowv) (*(const bf16x8*)&sBr[(rb_) * TB + (rowv) * 32 + (lq ^ (((rowv) >> 1) & 3)) * 8])

  floatx4 acc[FR][4] = {};

  STAGE_A(0); STAGE_B(0);
  STAGE_A(1); STAGE_B(1);
  STAGE_A(2); STAGE_B(2);
  if constexpr (LPT == 4) asm volatile("s_waitcnt vmcnt(8)" ::: "memory");
  else                    asm volatile("s_waitcnt vmcnt(6)" ::: "memory");
  __builtin_amdgcn_s_barrier();

#pragma unroll 4
  for (int T = 0; T < NT_PROJ; ++T) {
    const int rb = T & 3;
    bf16x8 af[4], bfr[4];
#pragma unroll
    for (int j = 0; j < 4; ++j) bfr[j] = BRD(rb, wn + j * 16 + lr);
#pragma unroll
    for (int i = 0; i < 4; ++i) af[i] = ARD(rb, wm + i * 16 + lr);
    if (T + 3 < NT_PROJ) {
      STAGE_A(T + 3);
      if constexpr (BMt == 128) STAGE_B(T + 3);
    }
    __builtin_amdgcn_s_barrier();
    __builtin_amdgcn_s_setprio(1);
#pragma unroll
    for (int i = 0; i < 4; ++i)
#pragma unroll
      for (int j = 0; j < 4; ++j)
        acc[i][j] = __builtin_amdgcn_mfma_f32_16x16x32_bf16(af[i], bfr[j], acc[i][j], 0, 0, 0);
    __builtin_amdgcn_s_setprio(0);
    if constexpr (BMt == 256) {
      __builtin_amdgcn_s_barrier();
#pragma unroll
      for (int i = 0; i < 4; ++i) af[i] = ARD(rb, wm + 64 + i * 16 + lr);
      if (T + 3 < NT_PROJ) STAGE_B(T + 3);
      __builtin_amdgcn_s_barrier();
      __builtin_amdgcn_s_setprio(1);
#pragma unroll
      for (int i = 0; i < 4; ++i)
#pragma unroll
        for (int j = 0; j < 4; ++j)
          acc[4 + i][j] = __builtin_amdgcn_mfma_f32_16x16x32_bf16(af[i], bfr[j], acc[4 + i][j], 0, 0, 0);
      __builtin_amdgcn_s_setprio(0);
    }
    if (T < NT_PROJ - 3) {
      if constexpr (LPT == 4) asm volatile("s_waitcnt vmcnt(8)" ::: "memory");
      else                    asm volatile("s_waitcnt vmcnt(6)" ::: "memory");
    } else if (T == NT_PROJ - 3) {
      if constexpr (LPT == 4) asm volatile("s_waitcnt vmcnt(4)" ::: "memory");
      else                    asm volatile("s_waitcnt vmcnt(3)" ::: "memory");
    } else if (T == NT_PROJ - 2) {
      asm volatile("s_waitcnt vmcnt(0)" ::: "memory");
    }
    __builtin_amdgcn_s_barrier();
  }
#undef STAGE_A
#undef STAGE_B
#undef ARD
#undef BRD

  if constexpr (MODE == 1) {
    // exp numerator + causal mask + rowsum atomics (layout identical to verified MODE1)
#pragma unroll
    for (int i = 0; i < FR; ++i) {
      int rbase = m0 + wm + i * 16 + lq * 4;
      float s0 = 0.f, s1 = 0.f, s2 = 0.f, s3 = 0.f;
#pragma unroll
      for (int j = 0; j < 4; ++j) {
        int col = n0 + wn + j * 16 + lr;
        float e0 = (col <= rbase + 0) ? __expf(acc[i][j][0] * scale) : 0.0f;
        float e1 = (col <= rbase + 1) ? __expf(acc[i][j][1] * scale) : 0.0f;
        float e2 = (col <= rbase + 2) ? __expf(acc[i][j][2] * scale) : 0.0f;
        float e3 = (col <= rbase + 3) ? __expf(acc[i][j][3] * scale) : 0.0f;
        C[(size_t)(rbase + 0) * ldc + col] = f2bf(e0);
        C[(size_t)(rbase + 1) * ldc + col] = f2bf(e1);
        C[(size_t)(rbase + 2) * ldc + col] = f2bf(e2);
        C[(size_t)(rbase + 3) * ldc + col] = f2bf(e3);
        s0 += e0; s1 += e1; s2 += e2; s3 += e3;
      }
#pragma unroll
      for (int m = 1; m < 16; m <<= 1) {
        s0 += __shfl_xor(s0, m, 64);
        s1 += __shfl_xor(s1, m, 64);
        s2 += __shfl_xor(s2, m, 64);
        s3 += __shfl_xor(s3, m, 64);
      }
      if (lr == 0) {
        atomicAdd(&rowsum[rbase + 0], s0);
        atomicAdd(&rowsum[rbase + 1], s1);
        atomicAdd(&rowsum[rbase + 2], s2);
        atomicAdd(&rowsum[rbase + 3], s3);
      }
    }
  } else {
#pragma unroll
    for (int i = 0; i < FR; ++i) {
      int rbase = m0 + wm + i * 16 + lq * 4;
#pragma unroll
      for (int j = 0; j < 4; ++j) {
        int col = n0 + wn + j * 16 + lr;
#pragma unroll
        for (int r = 0; r < 4; ++r)
          C[(size_t)(rbase + r) * ldc + col] = f2bf(acc[i][j][r]);
      }
    }
  }
}

__global__ __launch_bounds__(512, 2) void proj256(
    const unsigned short* __restrict__ Ebf,
    const unsigned short* __restrict__ WtQK,
    const unsigned short* __restrict__ WtV,
    unsigned short* __restrict__ QKo,
    unsigned short* __restrict__ Vt) {
  __shared__ __align__(16) unsigned short sA[32768];  // 64 KiB
  __shared__ __align__(16) unsigned short sB[32768];  // 64 KiB
  int x = blockIdx.x;
  if (x < 256) {
    proj8ph(Ebf, WtQK, QKo, 2 * DIM, (x >> 3) * 256, (x & 7) * 256, sA, sB);
  } else {
    x -= 256;
    proj_core<128>(WtV, DIM, Ebf, DIM, Vt, BSZ * SEQ, (x >> 5) * 128, (x & 31) * 256, sA, sB);
  }
}

// ---------------- NEW: scores on the 512-thread 128x256 ring core ----------------
// Tri grid at 256-wide columns: block (mt, nt) with nt <= mt/2; 72 blocks/batch.
// Coverage invariant verified: every k<=q entry lies in a written tile; diagonal
// overhang is masked to 0 (what PV's causal Keff expects).
__global__ __launch_bounds__(512, 2) void scores512(
    const unsigned short* __restrict__ QK,
    unsigned short* __restrict__ ExpS,
    float* __restrict__ Rsum) {
  __shared__ __align__(16) unsigned short sA[16384];  // 32 KiB
  __shared__ __align__(16) unsigned short sB[32768];  // 64 KiB
  int t = blockIdx.x, mt = 0, s = 0;
  while (s + (mt >> 1) + 1 <= t) { s += (mt >> 1) + 1; mt++; }
  int nt = t - s;
  const unsigned short* A = QK + (size_t)blockIdx.z * SEQ * 2 * DIM;
  proj_core<128, 1>(A, 2 * DIM, A + DIM, 2 * DIM,
                    ExpS + (size_t)blockIdx.z * SEQ * SEQ, SEQ,
                    mt * 128, nt * 256, sA, sB,
                    0.03125f /* 1/sqrt(1024) */,
                    Rsum + (size_t)blockIdx.z * SEQ);
}

// =====================================================================
// PV on the R2-proven ring-4 core (R5/R6-verified), 256-thread 128x128.
// MODE 2: causal Keff, complementary z-pairing.
// =====================================================================
template <typename OutT, int MODE>
__global__ __launch_bounds__(256, 2) void gemm_ring(
    const unsigned short* __restrict__ A, int lda, long long strideA,
    const unsigned short* __restrict__ B, int ldb, long long strideB,
    OutT* __restrict__ C, int ldc, long long strideC,
    int Kdim, float scale, float* __restrict__ rowsum) {
  int m0, n0;
  if constexpr (MODE == 1) {
    int t = blockIdx.x;
    int mt = 0;
    while (((mt + 1) * (mt + 2)) / 2 <= t) mt++;
    int nt = t - (mt * (mt + 1)) / 2;
    m0 = mt * 128; n0 = nt * 128;
  } else {
    int yy = ((blockIdx.z >> 1) & 1) ? blockIdx.y : (gridDim.y - 1 - blockIdx.y);
    m0 = yy * 128;
    n0 = blockIdx.x * 128;
  }
  const int Keff = (MODE == 2) ? min(Kdim, m0 + 128) : Kdim;
  const int NT = Keff >> 5;
  A += (long long)blockIdx.z * strideA;
  B += (long long)blockIdx.z * strideB;
  C += (long long)blockIdx.z * strideC;
  rowsum += (size_t)blockIdx.z * SEQ;

  __shared__ __align__(16) unsigned short sA[4 * 4096];  // 32 KiB
  __shared__ __align__(16) unsigned short sB[4 * 4096];  // 32 KiB

  const int tid = threadIdx.x;
  const int lane = tid & 63;
  const int wid = tid >> 6;
  const int wm = (wid >> 1) * 64, wn = (wid & 1) * 64;
  const int lr = lane & 15, lq = lane >> 4;

  const int schunk = (tid & 3) ^ ((tid >> 3) & 3);
  const unsigned short* gA = A + (size_t)(m0 + (tid >> 2)) * lda + schunk * 8;
  const unsigned short* gB = B + (size_t)(n0 + (tid >> 2)) * ldb + schunk * 8;
  unsigned short* lA = sA + wid * 512;
  unsigned short* lB = sB + wid * 512;
  const size_t sGA = (size_t)64 * lda, sGB = (size_t)64 * ldb;

#define RSTAGE(T) do { int rb_ = (T) & 3; \
    gload16(gA + (size_t)(T) * 32,       lA + rb_ * 4096); \
    gload16(gA + (size_t)(T) * 32 + sGA, lA + rb_ * 4096 + 2048); \
    gload16(gB + (size_t)(T) * 32,       lB + rb_ * 4096); \
    gload16(gB + (size_t)(T) * 32 + sGB, lB + rb_ * 4096 + 2048); } while (0)
#define RARD(rb_, rowv) (*(const bf16x8*)&sA[(rb_) * 4096 + (rowv) * 32 + (lq ^ (((rowv) >> 1) & 3)) * 8])
#define RBRD(rb_, rowv) (*(const bf16x8*)&sB[(rb_) * 4096 + (rowv) * 32 + (lq ^ (((rowv) >> 1) & 3)) * 8])

  floatx4 acc[4][4] = {};

  RSTAGE(0); RSTAGE(1); RSTAGE(2);
  asm volatile("s_waitcnt vmcnt(8)" ::: "memory");
  __builtin_amdgcn_s_barrier();

  for (int T = 0; T < NT; ++T) {
    const int rb = T & 3;
    bf16x8 af[4], bfr[4];
#pragma unroll
    for (int j = 0; j < 4; ++j) bfr[j] = RBRD(rb, wn + j * 16 + lr);
#pragma unroll
    for (int i = 0; i < 4; ++i) af[i] = RARD(rb, wm + i * 16 + lr);
    if (T + 3 < NT) RSTAGE(T + 3);
    __builtin_amdgcn_s_barrier();
    __builtin_amdgcn_s_setprio(1);
#pragma unroll
    for (int i = 0; i < 4; ++i)
#pragma unroll
      for (int j = 0; j < 4; ++j)
        acc[i][j] = __builtin_amdgcn_mfma_f32_16x16x32_bf16(af[i], bfr[j], acc[i][j], 0, 0, 0);
    __builtin_amdgcn_s_setprio(0);
    if (T < NT - 3)       asm volatile("s_waitcnt vmcnt(8)" ::: "memory");
    else if (T == NT - 3) asm volatile("s_waitcnt vmcnt(4)" ::: "memory");
    else if (T == NT - 2) asm volatile("s_waitcnt vmcnt(0)" ::: "memory");
    __builtin_amdgcn_s_barrier();
  }
#undef RSTAGE
#undef RARD
#undef RBRD

  if constexpr (MODE == 1) {
#pragma unroll
    for (int i = 0; i < 4; i++) {
      int rbase = m0 + wm + i * 16 + lq * 4;
      float s0 = 0.f, s1 = 0.f, s2 = 0.f, s3 = 0.f;
#pragma unroll
      for (int j = 0; j < 4; j++) {
        int col = n0 + wn + j * 16 + lr;
        float e0 = (col <= rbase + 0) ? __expf(acc[i][j][0] * scale) : 0.0f;
        float e1 = (col <= rbase + 1) ? __expf(acc[i][j][1] * scale) : 0.0f;
        float e2 = (col <= rbase + 2) ? __expf(acc[i][j][2] * scale) : 0.0f;
        float e3 = (col <= rbase + 3) ? __expf(acc[i][j][3] * scale) : 0.0f;
        store_c(&C[(size_t)(rbase + 0) * ldc + col], e0);
        store_c(&C[(size_t)(rbase + 1) * ldc + col], e1);
        store_c(&C[(size_t)(rbase + 2) * ldc + col], e2);
        store_c(&C[(size_t)(rbase + 3) * ldc + col], e3);
        s0 += e0; s1 += e1; s2 += e2; s3 += e3;
      }
#pragma unroll
      for (int m = 1; m < 16; m <<= 1) {
        s0 += __shfl_xor(s0, m, 64);
        s1 += __shfl_xor(s1, m, 64);
        s2 += __shfl_xor(s2, m, 64);
        s3 += __shfl_xor(s3, m, 64);
      }
      if (lr == 0) {
        atomicAdd(&rowsum[rbase + 0], s0);
        atomicAdd(&rowsum[rbase + 1], s1);
        atomicAdd(&rowsum[rbase + 2], s2);
        atomicAdd(&rowsum[rbase + 3], s3);
      }
    }
  } else {
#pragma unroll
    for (int i = 0; i < 4; i++) {
      int rbase = m0 + wm + i * 16 + lq * 4;
      float i0 = 1.0f / rowsum[rbase + 0];
      float i1 = 1.0f / rowsum[rbase + 1];
      float i2 = 1.0f / rowsum[rbase + 2];
      float i3 = 1.0f / rowsum[rbase + 3];
#pragma unroll
      for (int j = 0; j < 4; j++) {
        int col = n0 + wn + j * 16 + lr;
        store_c(&C[(size_t)(rbase + 0) * ldc + col], acc[i][j][0] * i0);
        store_c(&C[(size_t)(rbase + 1) * ldc + col], acc[i][j][1] * i1);
        store_c(&C[(size_t)(rbase + 2) * ldc + col], acc[i][j][2] * i2);
        store_c(&C[(size_t)(rbase + 3) * ldc + col], acc[i][j][3] * i3);
      }
    }
  }
}

extern "C" void kernel_launch(void* const* d_in, const int* in_sizes, int n_in,
                              void* d_out, int out_size, void* d_ws, size_t ws_size,
                              hipStream_t stream) {
  const float* E  = (const float*)d_in[0];
  const float* Wq = (const float*)d_in[1];
  const float* Wk = (const float*)d_in[2];
  const float* Wv = (const float*)d_in[3];
  float* out = (float*)d_out;

  char* ws = (char*)d_ws;
  size_t off = 0;
  auto alloc = [&](size_t bytes) {
    void* p = ws + off;
    off += (bytes + 255) & ~(size_t)255;
    return p;
  };
  const size_t M_ALL = (size_t)BSZ * SEQ;
  unsigned short* Ebf  = (unsigned short*)alloc(M_ALL * DIM * 2);
  unsigned short* WtQK = (unsigned short*)alloc((size_t)2 * DIM * DIM * 2);
  unsigned short* WtV  = (unsigned short*)alloc((size_t)DIM * DIM * 2);
  unsigned short* QK   = (unsigned short*)alloc(M_ALL * 2 * DIM * 2);
  unsigned short* Vt   = (unsigned short*)alloc((size_t)DIM * M_ALL * 2);
  unsigned short* ExpS = (unsigned short*)alloc((size_t)BSZ * SEQ * SEQ * 2);
  float*          Rsum = (float*)alloc((size_t)BSZ * SEQ * 4);

  int nE = (int)(M_ALL * DIM);
  // merged: cast E + zero Rsum + transpose weights (R6-verified)
  prep<<<dim3(11264), dim3(256), 0, stream>>>(E, Wq, Wk, Wv, Ebf, WtQK, WtV, Rsum, nE);

  // fused QK (256 blocks, 8-phase core) + Vt (256 half-work blocks, ring core)
  proj256<<<dim3(512), dim3(512), 0, stream>>>(Ebf, WtQK, WtV, QK, Vt);

  // scores -> exp numerators + rowsum atomics; 512-thr 128x256 tri grid (72/batch)
  scores512<<<dim3(72, 1, BSZ), dim3(512), 0, stream>>>(QK, ExpS, Rsum);

  // PV: out[q][d] = (sum_k expS[q][k] * Vt[d][k]) / rowsum[q]
  gemm_ring<float, 2><<<dim3(8, 16, BSZ), dim3(256), 0, stream>>>(
      ExpS, SEQ, (long long)SEQ * SEQ,
      Vt, (int)M_ALL, (long long)SEQ,
      out, DIM, (long long)SEQ * DIM,
      SEQ, 1.0f, Rsum);
}

// Round 10
// 225.295 us; speedup vs baseline: 1.0839x; 1.0367x over previous
//
#include <hip/hip_runtime.h>
#include <hip/hip_bf16.h>

#define BSZ 4
#define SEQ 2048
#define DIM 1024

typedef __attribute__((ext_vector_type(8))) short bf16x8;
typedef __attribute__((ext_vector_type(4))) float floatx4;

__device__ __forceinline__ unsigned short f2bf(float x) {
  union { float f; unsigned int u; } v; v.f = x;
  unsigned int r = v.u + 0x7fffu + ((v.u >> 16) & 1u);
  return (unsigned short)(r >> 16);
}

template <typename T> __device__ __forceinline__ void store_c(T* p, float v);
template <> __device__ __forceinline__ void store_c<float>(float* p, float v) { *p = v; }
template <> __device__ __forceinline__ void store_c<unsigned short>(unsigned short* p, float v) { *p = f2bf(v); }

// ---------------- merged prep (R6-verified): cast E + zero Rsum + transpose weights ----------------
__global__ __launch_bounds__(256) void prep(const float* __restrict__ E,
                                            const float* __restrict__ Wq,
                                            const float* __restrict__ Wk,
                                            const float* __restrict__ Wv,
                                            unsigned short* __restrict__ Ebf,
                                            unsigned short* __restrict__ WtQK,
                                            unsigned short* __restrict__ WtV,
                                            float* __restrict__ rsum, int n) {
  __shared__ float tile[32][33];
  int b = blockIdx.x;
  int tid = threadIdx.x;
  if (b < 8192) {
    if (b < 8) {
      int j = b * 1024 + tid * 4;
      *(float4*)(rsum + j) = make_float4(0.f, 0.f, 0.f, 0.f);
    }
    int i = (b * 256 + tid) * 4;
    if (i >= n) return;
    float4 v = *(const float4*)(E + i);
    ushort4 o;
    o.x = f2bf(v.x); o.y = f2bf(v.y); o.z = f2bf(v.z); o.w = f2bf(v.w);
    *(ushort4*)(Ebf + i) = o;
  } else {
    b -= 8192;
    int z = b >> 10;             // 0..2
    int rb = b & 1023;
    int bx = rb & 31, by = rb >> 5;
    const float* W = (z == 0) ? Wq : (z == 1) ? Wk : Wv;
    unsigned short* dst = (z == 2) ? WtV : WtQK;
    int row_off = (z == 1) ? 1024 : 0;
    int n0 = bx * 32, k0 = by * 32;
    int tx = tid & 31, ty = tid >> 5;   // 32 x 8
    for (int r = ty; r < 32; r += 8)
      tile[r][tx] = W[(size_t)(k0 + r) * DIM + n0 + tx];
    __syncthreads();
    for (int r = ty; r < 32; r += 8)
      dst[(size_t)(row_off + n0 + r) * DIM + k0 + tx] = f2bf(tile[tx][r]);
  }
}

__device__ __forceinline__ void gload16(const unsigned short* g, unsigned short* l) {
  __builtin_amdgcn_global_load_lds(
      (const __attribute__((address_space(1))) unsigned int*)g,
      (__attribute__((address_space(3))) unsigned int*)l, 16, 0, 0);
}

// =====================================================================
// 8-phase 256x256 GEMM core — R4-verified schedule, FROZEN.
// R10: parameterized lda/ldb (address math only) + MODE template:
//   MODE 0 = plain bf16 store (QK path, unchanged behavior)
//   MODE 1 = exp/causal-mask/rowsum epilogue (scores path)
// =====================================================================
template <int MODE = 0>
__device__ __forceinline__ void proj8ph(
    const unsigned short* __restrict__ A, int lda,
    const unsigned short* __restrict__ Bm, int ldb,
    unsigned short* __restrict__ C, int ldc, int m0, int n0,
    unsigned short* sA, unsigned short* sB,
    float scale = 0.f, float* __restrict__ rowsum = nullptr) {
  const int tid = threadIdx.x;
  const int lane = tid & 63;
  const int wid = tid >> 6;            // 0..7
  const int wm = (wid >> 2) * 128;     // 0 / 128
  const int wn = (wid & 3) * 64;       // 0/64/128/192
  const int lr = lane & 15, lq = lane >> 4;

  unsigned short* aB = sA + (wm >> 7) * 8192 + lr * 64;
  unsigned short* bB = sB + (wn >> 7) * 8192 + ((wn & 64) + lr) * 64;
  const int sw0 = (lq ^ (lr & 7)) * 8;
  const int sw1 = ((4 + lq) ^ (lr & 7)) * 8;

  const int schunk = (tid & 7) ^ ((tid >> 3) & 7);
  const unsigned short* gA = A + (size_t)(m0 + (tid >> 3)) * lda + schunk * 8;
  const unsigned short* gB = Bm + (size_t)(n0 + (tid >> 3)) * ldb + schunk * 8;
  unsigned short* lA = sA + wid * 512;
  unsigned short* lB = sB + wid * 512;

#define STG_A(buf, T, half) do { \
    gload16(gA + (size_t)((half) * 128) * lda + (T) * 64,      lA + (buf) * 16384 + (half) * 8192); \
    gload16(gA + (size_t)((half) * 128 + 64) * lda + (T) * 64, lA + (buf) * 16384 + (half) * 8192 + 4096); } while (0)
#define STG_B(buf, T, half) do { \
    gload16(gB + (size_t)((half) * 128) * ldb + (T) * 64,      lB + (buf) * 16384 + (half) * 8192); \
    gload16(gB + (size_t)((half) * 128 + 64) * ldb + (T) * 64, lB + (buf) * 16384 + (half) * 8192 + 4096); } while (0)
#define RD_A(buf, qr) do { _Pragma("unroll") for (int i_ = 0; i_ < 4; ++i_) { \
    af[i_][0] = *(const bf16x8*)(aB + (buf) * 16384 + ((qr) * 64 + i_ * 16) * 64 + sw0); \
    af[i_][1] = *(const bf16x8*)(aB + (buf) * 16384 + ((qr) * 64 + i_ * 16) * 64 + sw1); } } while (0)
#define RD_B(buf, qc) do { _Pragma("unroll") for (int j_ = 0; j_ < 2; ++j_) { \
    bq[qc][j_][0] = *(const bf16x8*)(bB + (buf) * 16384 + ((qc) * 32 + j_ * 16) * 64 + sw0); \
    bq[qc][j_][1] = *(const bf16x8*)(bB + (buf) * 16384 + ((qc) * 32 + j_ * 16) * 64 + sw1); } } while (0)
#define MM(qr, qc) do { __builtin_amdgcn_s_setprio(1); \
    _Pragma("unroll") for (int i_ = 0; i_ < 4; ++i_) \
    _Pragma("unroll") for (int jj_ = 0; jj_ < 2; ++jj_) { \
      acc[(qr)*4+i_][(qc)*2+jj_] = __builtin_amdgcn_mfma_f32_16x16x32_bf16(af[i_][0], bq[qc][jj_][0], acc[(qr)*4+i_][(qc)*2+jj_], 0, 0, 0); \
      acc[(qr)*4+i_][(qc)*2+jj_] = __builtin_amdgcn_mfma_f32_16x16x32_bf16(af[i_][1], bq[qc][jj_][1], acc[(qr)*4+i_][(qc)*2+jj_], 0, 0, 0); } \
    __builtin_amdgcn_s_setprio(0); } while (0)
#define BAR __builtin_amdgcn_s_barrier()
#define LGKM0 do { asm volatile("s_waitcnt lgkmcnt(0)" ::: "memory"); __builtin_amdgcn_sched_barrier(0); } while (0)
#define VM4 asm volatile("s_waitcnt vmcnt(4)" ::: "memory")
#define VM0 asm volatile("s_waitcnt vmcnt(0)" ::: "memory")

  floatx4 acc[8][4] = {};
  bf16x8 af[4][2], bq[2][2][2];

  STG_B(0, 0, 0); STG_B(0, 0, 1);
  STG_A(0, 0, 0); STG_A(0, 0, 1);
  STG_B(1, 1, 0); STG_B(1, 1, 1);
  VM4;
  BAR;

#pragma unroll 1
  for (int j = 0; j < 8; ++j) {
    const int t0 = 2 * j, t1 = 2 * j + 1;
    const bool st = (j < 7);
    RD_A(0, 0); RD_B(0, 0);
    STG_A(1, t1, 0);
    BAR; LGKM0; MM(0, 0); BAR;

    RD_B(0, 1);
    STG_A(1, t1, 1);
    BAR; LGKM0; MM(0, 1); BAR;

    RD_A(0, 1);
    if (st) STG_B(0, t0 + 2, 0);
    BAR; LGKM0; MM(1, 0); BAR;

    if (st) STG_B(0, t0 + 2, 1);
    BAR; MM(1, 1);
    if (st) { VM4; } else { VM0; }
    BAR;

    RD_A(1, 0); RD_B(1, 0);
    if (st) STG_A(0, t0 + 2, 0);
    BAR; LGKM0; MM(0, 0); BAR;

    RD_B(1, 1);
    if (st) STG_A(0, t0 + 2, 1);
    BAR; LGKM0; MM(0, 1); BAR;

    RD_A(1, 1);
    if (st) STG_B(1, t1 + 2, 0);
    BAR; LGKM0; MM(1, 0); BAR;

    if (st) STG_B(1, t1 + 2, 1);
    BAR; MM(1, 1);
    if (st) { VM4; }
    BAR;
  }
#undef STG_A
#undef STG_B
#undef RD_A
#undef RD_B
#undef MM
#undef BAR
#undef LGKM0
#undef VM4
#undef VM0

  if constexpr (MODE == 1) {
    // exp numerator + causal mask + rowsum atomics on the verified C/D layout
#pragma unroll
    for (int i = 0; i < 8; ++i) {
      int rbase = m0 + wm + i * 16 + lq * 4;
      float s0 = 0.f, s1 = 0.f, s2 = 0.f, s3 = 0.f;
#pragma unroll
      for (int jc = 0; jc < 4; ++jc) {
        int col = n0 + wn + jc * 16 + lr;
        float e0 = (col <= rbase + 0) ? __expf(acc[i][jc][0] * scale) : 0.0f;
        float e1 = (col <= rbase + 1) ? __expf(acc[i][jc][1] * scale) : 0.0f;
        float e2 = (col <= rbase + 2) ? __expf(acc[i][jc][2] * scale) : 0.0f;
        float e3 = (col <= rbase + 3) ? __expf(acc[i][jc][3] * scale) : 0.0f;
        C[(size_t)(rbase + 0) * ldc + col] = f2bf(e0);
        C[(size_t)(rbase + 1) * ldc + col] = f2bf(e1);
        C[(size_t)(rbase + 2) * ldc + col] = f2bf(e2);
        C[(size_t)(rbase + 3) * ldc + col] = f2bf(e3);
        s0 += e0; s1 += e1; s2 += e2; s3 += e3;
      }
#pragma unroll
      for (int m = 1; m < 16; m <<= 1) {
        s0 += __shfl_xor(s0, m, 64);
        s1 += __shfl_xor(s1, m, 64);
        s2 += __shfl_xor(s2, m, 64);
        s3 += __shfl_xor(s3, m, 64);
      }
      if (lr == 0) {
        atomicAdd(&rowsum[rbase + 0], s0);
        atomicAdd(&rowsum[rbase + 1], s1);
        atomicAdd(&rowsum[rbase + 2], s2);
        atomicAdd(&rowsum[rbase + 3], s3);
      }
    }
  } else {
#pragma unroll
    for (int i = 0; i < 8; ++i) {
      int rbase = m0 + wm + i * 16 + lq * 4;
#pragma unroll
      for (int jc = 0; jc < 4; ++jc) {
        int col = n0 + wn + jc * 16 + lr;
#pragma unroll
        for (int r = 0; r < 4; ++r)
          C[(size_t)(rbase + r) * ldc + col] = f2bf(acc[i][jc][r]);
      }
    }
  }
}

// ---------------- R2-proven ring-4 core — FROZEN schedule, lda/ldb-parameterized ----------------
#define NT_PROJ 32  // K=1024 / BK=32

template <int BMt, int MODE = 0>
__device__ __forceinline__ void proj_core(
    const unsigned short* __restrict__ A, int lda,
    const unsigned short* __restrict__ Bm, int ldb,
    unsigned short* __restrict__ C, int ldc, int m0, int n0,
    unsigned short* sAr, unsigned short* sBr,
    float scale = 0.f, float* __restrict__ rowsum = nullptr) {
  constexpr int LPA = BMt / 128;
  constexpr int LPT = LPA + 2;
  constexpr int FR  = BMt / 32;
  constexpr int TA  = BMt * 32;
  constexpr int TB  = 256 * 32;

  const int tid = threadIdx.x;
  const int lane = tid & 63;
  const int wid = tid >> 6;
  const int wm = (wid >> 2) * (BMt / 2);
  const int wn = (wid & 3) * 64;
  const int lr = lane & 15, lq = lane >> 4;

  const int srow = tid >> 2;
  const int schunk = (tid & 3) ^ ((tid >> 3) & 3);
  const unsigned short* gA = A + (size_t)(m0 + srow) * lda + schunk * 8;
  const unsigned short* gB = Bm + (size_t)(n0 + srow) * ldb + schunk * 8;
  unsigned short* lA = sAr + 16 * 32 * wid;
  unsigned short* lB = sBr + 16 * 32 * wid;
  const size_t swGA = (size_t)128 * lda;
  const size_t swGB = (size_t)128 * ldb;

#define STAGE_A(T) do { int rb_ = (T) & 3; \
    gload16(gA + (size_t)(T) * 32, lA + rb_ * TA); \
    if constexpr (LPA == 2) gload16(gA + (size_t)(T) * 32 + swGA, lA + rb_ * TA + 4096); } while (0)
#define STAGE_B(T) do { int rb_ = (T) & 3; \
    gload16(gB + (size_t)(T) * 32,        lB + rb_ * TB); \
    gload16(gB + (size_t)(T) * 32 + swGB, lB + rb_ * TB + 4096); } while (0)
#define ARD(rb_, rowv) (*(const bf16x8*)&sAr[(rb_) * TA + (rowv) * 32 + (lq ^ (((rowv) >> 1) & 3)) * 8])
#define BRD(rb_, rowv) (*(const bf16x8*)&sBr[(rb_) * TB + (rowv) * 32 + (lq ^ (((rowv) >> 1) & 3)) * 8])

  floatx4 acc[FR][4] = {};

  STAGE_A(0); STAGE_B(0);
  STAGE_A(1); STAGE_B(1);
  STAGE_A(2); STAGE_B(2);
  if constexpr (LPT == 4) asm volatile("s_waitcnt vmcnt(8)" ::: "memory");
  else                    asm volatile("s_waitcnt vmcnt(6)" ::: "memory");
  __builtin_amdgcn_s_barrier();

#pragma unroll 4
  for (int T = 0; T < NT_PROJ; ++T) {
    const int rb = T & 3;
    bf16x8 af[4], bfr[4];
#pragma unroll
    for (int j = 0; j < 4; ++j) bfr[j] = BRD(rb, wn + j * 16 + lr);
#pragma unroll
    for (int i = 0; i < 4; ++i) af[i] = ARD(rb, wm + i * 16 + lr);
    if (T + 3 < NT_PROJ) {
      STAGE_A(T + 3);
      if constexpr (BMt == 128) STAGE_B(T + 3);
    }
    __builtin_amdgcn_s_barrier();
    __builtin_amdgcn_s_setprio(1);
#pragma unroll
    for (int i = 0; i < 4; ++i)
#pragma unroll
      for (int j = 0; j < 4; ++j)
        acc[i][j] = __builtin_amdgcn_mfma_f32_16x16x32_bf16(af[i], bfr[j], acc[i][j], 0, 0, 0);
    __builtin_amdgcn_s_setprio(0);
    if constexpr (BMt == 256) {
      __builtin_amdgcn_s_barrier();
#pragma unroll
      for (int i = 0; i < 4; ++i) af[i] = ARD(rb, wm + 64 + i * 16 + lr);
      if (T + 3 < NT_PROJ) STAGE_B(T + 3);
      __builtin_amdgcn_s_barrier();
      __builtin_amdgcn_s_setprio(1);
#pragma unroll
      for (int i = 0; i < 4; ++i)
#pragma unroll
        for (int j = 0; j < 4; ++j)
          acc[4 + i][j] = __builtin_amdgcn_mfma_f32_16x16x32_bf16(af[i], bfr[j], acc[4 + i][j], 0, 0, 0);
      __builtin_amdgcn_s_setprio(0);
    }
    if (T < NT_PROJ - 3) {
      if constexpr (LPT == 4) asm volatile("s_waitcnt vmcnt(8)" ::: "memory");
      else                    asm volatile("s_waitcnt vmcnt(6)" ::: "memory");
    } else if (T == NT_PROJ - 3) {
      if constexpr (LPT == 4) asm volatile("s_waitcnt vmcnt(4)" ::: "memory");
      else                    asm volatile("s_waitcnt vmcnt(3)" ::: "memory");
    } else if (T == NT_PROJ - 2) {
      asm volatile("s_waitcnt vmcnt(0)" ::: "memory");
    }
    __builtin_amdgcn_s_barrier();
  }
#undef STAGE_A
#undef STAGE_B
#undef ARD
#undef BRD

#pragma unroll
  for (int i = 0; i < FR; ++i) {
    int rbase = m0 + wm + i * 16 + lq * 4;
#pragma unroll
    for (int j = 0; j < 4; ++j) {
      int col = n0 + wn + j * 16 + lr;
#pragma unroll
      for (int r = 0; r < 4; ++r)
        C[(size_t)(rbase + r) * ldc + col] = f2bf(acc[i][j][r]);
    }
  }
}

__global__ __launch_bounds__(512, 2) void proj256(
    const unsigned short* __restrict__ Ebf,
    const unsigned short* __restrict__ WtQK,
    const unsigned short* __restrict__ WtV,
    unsigned short* __restrict__ QKo,
    unsigned short* __restrict__ Vt) {
  __shared__ __align__(16) unsigned short sA[32768];  // 64 KiB
  __shared__ __align__(16) unsigned short sB[32768];  // 64 KiB
  int x = blockIdx.x;
  if (x < 256) {
    proj8ph<0>(Ebf, DIM, WtQK, DIM, QKo, 2 * DIM, (x >> 3) * 256, (x & 7) * 256, sA, sB);
  } else {
    x -= 256;
    proj_core<128>(WtV, DIM, Ebf, DIM, Vt, BSZ * SEQ, (x >> 5) * 128, (x & 31) * 256, sA, sB);
  }
}

// ---------------- scores on the 8-phase 256x256 core: 36 tiles/batch, ONE round ----------------
// Tri grid (nt <= mt) at 256x256 tiles: 144 blocks total at 1 block/CU -> single round.
// Diagonal overhang masked to exp->0 (exactly what PV's causal Keff expects).
__global__ __launch_bounds__(512, 2) void scores256(
    const unsigned short* __restrict__ QK,
    unsigned short* __restrict__ ExpS,
    float* __restrict__ Rsum) {
  __shared__ __align__(16) unsigned short sA[32768];  // 64 KiB
  __shared__ __align__(16) unsigned short sB[32768];  // 64 KiB
  int t = blockIdx.x;                 // 0..35
  int mt = 0;
  while (((mt + 1) * (mt + 2)) / 2 <= t) mt++;
  int nt = t - (mt * (mt + 1)) / 2;
  const unsigned short* A = QK + (size_t)blockIdx.z * SEQ * 2 * DIM;
  proj8ph<1>(A, 2 * DIM, A + DIM, 2 * DIM,
             ExpS + (size_t)blockIdx.z * SEQ * SEQ, SEQ,
             mt * 256, nt * 256, sA, sB,
             0.03125f /* 1/sqrt(1024) */,
             Rsum + (size_t)blockIdx.z * SEQ);
}

// =====================================================================
// PV on the R2-proven ring-4 core (R5/R6-verified), 256-thread 128x128.
// MODE 2: causal Keff, complementary z-pairing.
// =====================================================================
template <typename OutT, int MODE>
__global__ __launch_bounds__(256, 2) void gemm_ring(
    const unsigned short* __restrict__ A, int lda, long long strideA,
    const unsigned short* __restrict__ B, int ldb, long long strideB,
    OutT* __restrict__ C, int ldc, long long strideC,
    int Kdim, float scale, float* __restrict__ rowsum) {
  int m0, n0;
  if constexpr (MODE == 1) {
    int t = blockIdx.x;
    int mt = 0;
    while (((mt + 1) * (mt + 2)) / 2 <= t) mt++;
    int nt = t - (mt * (mt + 1)) / 2;
    m0 = mt * 128; n0 = nt * 128;
  } else {
    int yy = ((blockIdx.z >> 1) & 1) ? blockIdx.y : (gridDim.y - 1 - blockIdx.y);
    m0 = yy * 128;
    n0 = blockIdx.x * 128;
  }
  const int Keff = (MODE == 2) ? min(Kdim, m0 + 128) : Kdim;
  const int NT = Keff >> 5;
  A += (long long)blockIdx.z * strideA;
  B += (long long)blockIdx.z * strideB;
  C += (long long)blockIdx.z * strideC;
  rowsum += (size_t)blockIdx.z * SEQ;

  __shared__ __align__(16) unsigned short sA[4 * 4096];  // 32 KiB
  __shared__ __align__(16) unsigned short sB[4 * 4096];  // 32 KiB

  const int tid = threadIdx.x;
  const int lane = tid & 63;
  const int wid = tid >> 6;
  const int wm = (wid >> 1) * 64, wn = (wid & 1) * 64;
  const int lr = lane & 15, lq = lane >> 4;

  const int schunk = (tid & 3) ^ ((tid >> 3) & 3);
  const unsigned short* gA = A + (size_t)(m0 + (tid >> 2)) * lda + schunk * 8;
  const unsigned short* gB = B + (size_t)(n0 + (tid >> 2)) * ldb + schunk * 8;
  unsigned short* lA = sA + wid * 512;
  unsigned short* lB = sB + wid * 512;
  const size_t sGA = (size_t)64 * lda, sGB = (size_t)64 * ldb;

#define RSTAGE(T) do { int rb_ = (T) & 3; \
    gload16(gA + (size_t)(T) * 32,       lA + rb_ * 4096); \
    gload16(gA + (size_t)(T) * 32 + sGA, lA + rb_ * 4096 + 2048); \
    gload16(gB + (size_t)(T) * 32,       lB + rb_ * 4096); \
    gload16(gB + (size_t)(T) * 32 + sGB, lB + rb_ * 4096 + 2048); } while (0)
#define RARD(rb_, rowv) (*(const bf16x8*)&sA[(rb_) * 4096 + (rowv) * 32 + (lq ^ (((rowv) >> 1) & 3)) * 8])
#define RBRD(rb_, rowv) (*(const bf16x8*)&sB[(rb_) * 4096 + (rowv) * 32 + (lq ^ (((rowv) >> 1) & 3)) * 8])

  floatx4 acc[4][4] = {};

  RSTAGE(0); RSTAGE(1); RSTAGE(2);
  asm volatile("s_waitcnt vmcnt(8)" ::: "memory");
  __builtin_amdgcn_s_barrier();

  for (int T = 0; T < NT; ++T) {
    const int rb = T & 3;
    bf16x8 af[4], bfr[4];
#pragma unroll
    for (int j = 0; j < 4; ++j) bfr[j] = RBRD(rb, wn + j * 16 + lr);
#pragma unroll
    for (int i = 0; i < 4; ++i) af[i] = RARD(rb, wm + i * 16 + lr);
    if (T + 3 < NT) RSTAGE(T + 3);
    __builtin_amdgcn_s_barrier();
    __builtin_amdgcn_s_setprio(1);
#pragma unroll
    for (int i = 0; i < 4; ++i)
#pragma unroll
      for (int j = 0; j < 4; ++j)
        acc[i][j] = __builtin_amdgcn_mfma_f32_16x16x32_bf16(af[i], bfr[j], acc[i][j], 0, 0, 0);
    __builtin_amdgcn_s_setprio(0);
    if (T < NT - 3)       asm volatile("s_waitcnt vmcnt(8)" ::: "memory");
    else if (T == NT - 3) asm volatile("s_waitcnt vmcnt(4)" ::: "memory");
    else if (T == NT - 2) asm volatile("s_waitcnt vmcnt(0)" ::: "memory");
    __builtin_amdgcn_s_barrier();
  }
#undef RSTAGE
#undef RARD
#undef RBRD

  if constexpr (MODE == 1) {
#pragma unroll
    for (int i = 0; i < 4; i++) {
      int rbase = m0 + wm + i * 16 + lq * 4;
      float s0 = 0.f, s1 = 0.f, s2 = 0.f, s3 = 0.f;
#pragma unroll
      for (int j = 0; j < 4; j++) {
        int col = n0 + wn + j * 16 + lr;
        float e0 = (col <= rbase + 0) ? __expf(acc[i][j][0] * scale) : 0.0f;
        float e1 = (col <= rbase + 1) ? __expf(acc[i][j][1] * scale) : 0.0f;
        float e2 = (col <= rbase + 2) ? __expf(acc[i][j][2] * scale) : 0.0f;
        float e3 = (col <= rbase + 3) ? __expf(acc[i][j][3] * scale) : 0.0f;
        store_c(&C[(size_t)(rbase + 0) * ldc + col], e0);
        store_c(&C[(size_t)(rbase + 1) * ldc + col], e1);
        store_c(&C[(size_t)(rbase + 2) * ldc + col], e2);
        store_c(&C[(size_t)(rbase + 3) * ldc + col], e3);
        s0 += e0; s1 += e1; s2 += e2; s3 += e3;
      }
#pragma unroll
      for (int m = 1; m < 16; m <<= 1) {
        s0 += __shfl_xor(s0, m, 64);
        s1 += __shfl_xor(s1, m, 64);
        s2 += __shfl_xor(s2, m, 64);
        s3 += __shfl_xor(s3, m, 64);
      }
      if (lr == 0) {
        atomicAdd(&rowsum[rbase + 0], s0);
        atomicAdd(&rowsum[rbase + 1], s1);
        atomicAdd(&rowsum[rbase + 2], s2);
        atomicAdd(&rowsum[rbase + 3], s3);
      }
    }
  } else {
#pragma unroll
    for (int i = 0; i < 4; i++) {
      int rbase = m0 + wm + i * 16 + lq * 4;
      float i0 = 1.0f / rowsum[rbase + 0];
      float i1 = 1.0f / rowsum[rbase + 1];
      float i2 = 1.0f / rowsum[rbase + 2];
      float i3 = 1.0f / rowsum[rbase + 3];
#pragma unroll
      for (int j = 0; j < 4; j++) {
        int col = n0 + wn + j * 16 + lr;
        store_c(&C[(size_t)(rbase + 0) * ldc + col], acc[i][j][0] * i0);
        store_c(&C[(size_t)(rbase + 1) * ldc + col], acc[i][j][1] * i1);
        store_c(&C[(size_t)(rbase + 2) * ldc + col], acc[i][j][2] * i2);
        store_c(&C[(size_t)(rbase + 3) * ldc + col], acc[i][j][3] * i3);
      }
    }
  }
}

extern "C" void kernel_launch(void* const* d_in, const int* in_sizes, int n_in,
                              void* d_out, int out_size, void* d_ws, size_t ws_size,
                              hipStream_t stream) {
  const float* E  = (const float*)d_in[0];
  const float* Wq = (const float*)d_in[1];
  const float* Wk = (const float*)d_in[2];
  const float* Wv = (const float*)d_in[3];
  float* out = (float*)d_out;

  char* ws = (char*)d_ws;
  size_t off = 0;
  auto alloc = [&](size_t bytes) {
    void* p = ws + off;
    off += (bytes + 255) & ~(size_t)255;
    return p;
  };
  const size_t M_ALL = (size_t)BSZ * SEQ;
  unsigned short* Ebf  = (unsigned short*)alloc(M_ALL * DIM * 2);
  unsigned short* WtQK = (unsigned short*)alloc((size_t)2 * DIM * DIM * 2);
  unsigned short* WtV  = (unsigned short*)alloc((size_t)DIM * DIM * 2);
  unsigned short* QK   = (unsigned short*)alloc(M_ALL * 2 * DIM * 2);
  unsigned short* Vt   = (unsigned short*)alloc((size_t)DIM * M_ALL * 2);
  unsigned short* ExpS = (unsigned short*)alloc((size_t)BSZ * SEQ * SEQ * 2);
  float*          Rsum = (float*)alloc((size_t)BSZ * SEQ * 4);

  int nE = (int)(M_ALL * DIM);
  // merged: cast E + zero Rsum + transpose weights (R6-verified)
  prep<<<dim3(11264), dim3(256), 0, stream>>>(E, Wq, Wk, Wv, Ebf, WtQK, WtV, Rsum, nE);

  // fused QK (256 blocks, 8-phase core) + Vt (256 half-work blocks, ring core)
  proj256<<<dim3(512), dim3(512), 0, stream>>>(Ebf, WtQK, WtV, QK, Vt);

  // scores -> exp numerators + rowsum atomics; 256^2 8-phase tri grid, ONE round
  scores256<<<dim3(36, 1, BSZ), dim3(512), 0, stream>>>(QK, ExpS, Rsum);

  // PV: out[q][d] = (sum_k expS[q][k] * Vt[d][k]) / rowsum[q]
  gemm_ring<float, 2><<<dim3(8, 16, BSZ), dim3(256), 0, stream>>>(
      ExpS, SEQ, (long long)SEQ * SEQ,
      Vt, (int)M_ALL, (long long)SEQ,
      out, DIM, (long long)SEQ * DIM,
      SEQ, 1.0f, Rsum);
}

// Round 11
// 221.462 us; speedup vs baseline: 1.1027x; 1.0173x over previous
//
#include <hip/hip_runtime.h>
#include <hip/hip_bf16.h>

#define BSZ 4
#define SEQ 2048
#define DIM 1024

typedef __attribute__((ext_vector_type(8))) short bf16x8;
typedef __attribute__((ext_vector_type(4))) float floatx4;

__device__ __forceinline__ unsigned short f2bf(float x) {
  union { float f; unsigned int u; } v; v.f = x;
  unsigned int r = v.u + 0x7fffu + ((v.u >> 16) & 1u);
  return (unsigned short)(r >> 16);
}

// load 8 consecutive fp32, round to bf16, pack as uint4 (bf16x8 memory image)
__device__ __forceinline__ uint4 ld8f(const float* p) {
  float4 a = *(const float4*)p;
  float4 b = *(const float4*)(p + 4);
  uint4 u;
  u.x = (unsigned)f2bf(a.x) | ((unsigned)f2bf(a.y) << 16);
  u.y = (unsigned)f2bf(a.z) | ((unsigned)f2bf(a.w) << 16);
  u.z = (unsigned)f2bf(b.x) | ((unsigned)f2bf(b.y) << 16);
  u.w = (unsigned)f2bf(b.z) | ((unsigned)f2bf(b.w) << 16);
  return u;
}

template <typename T> __device__ __forceinline__ void store_c(T* p, float v);
template <> __device__ __forceinline__ void store_c<float>(float* p, float v) { *p = v; }
template <> __device__ __forceinline__ void store_c<unsigned short>(unsigned short* p, float v) { *p = f2bf(v); }

// =====================================================================
// prep (R8-verbatim, numerically proven): Mt = Wk x Wq^T (64 reg-staged
// MFMA blocks, fp32 inputs via ld8f), cast E -> bf16 (+ zero Rsum),
// transpose+cast Wv -> WtV. Mt blocks grid-first, co-resident with the
// BW-bound cast (36.8 KB LDS -> 4 blocks/CU).
// =====================================================================
__global__ __launch_bounds__(256) void prep(const float* __restrict__ E,
                                            const float* __restrict__ Wq,
                                            const float* __restrict__ Wk,
                                            const float* __restrict__ Wv,
                                            unsigned short* __restrict__ Ebf,
                                            unsigned short* __restrict__ WtV,
                                            unsigned short* __restrict__ Mt,
                                            float* __restrict__ rsum) {
  __shared__ __align__(16) unsigned short As[128][72];
  __shared__ __align__(16) unsigned short Bs[128][72];
  int b = blockIdx.x;
  int tid = threadIdx.x;

  if (b < 64) {
    // ---- Mt[j][i] = sum_d Wk[j,d] * Wq[i,d]  (so EM = Ebf x Mt^T = Q Wk^T) ----
    int m0 = (b >> 3) * 128, n0 = (b & 7) * 128;
    int lane = tid & 63;
    int wid = tid >> 6;
    int wm = (wid >> 1) * 64, wn = (wid & 1) * 64;
    int lr = lane & 15, lq = lane >> 4;
    int row = tid >> 3;
    int kc = (tid & 7) * 8;

    const float* Ab = Wk + (size_t)(m0 + row) * DIM + kc;
    const float* Bb = Wq + (size_t)(n0 + row) * DIM + kc;
    size_t la = (size_t)32 * DIM;

    uint4 ra0 = ld8f(Ab);
    uint4 ra1 = ld8f(Ab + la);
    uint4 ra2 = ld8f(Ab + 2 * la);
    uint4 ra3 = ld8f(Ab + 3 * la);
    uint4 rb0 = ld8f(Bb);
    uint4 rb1 = ld8f(Bb + la);
    uint4 rb2 = ld8f(Bb + 2 * la);
    uint4 rb3 = ld8f(Bb + 3 * la);

    floatx4 acc[4][4] = {};

    for (int k0 = 0; k0 < DIM; k0 += 64) {
      __syncthreads();
      *(uint4*)&As[row][kc]      = ra0;
      *(uint4*)&As[row + 32][kc] = ra1;
      *(uint4*)&As[row + 64][kc] = ra2;
      *(uint4*)&As[row + 96][kc] = ra3;
      *(uint4*)&Bs[row][kc]      = rb0;
      *(uint4*)&Bs[row + 32][kc] = rb1;
      *(uint4*)&Bs[row + 64][kc] = rb2;
      *(uint4*)&Bs[row + 96][kc] = rb3;
      if (k0 + 64 < DIM) {
        const float* An = Ab + k0 + 64;
        const float* Bn = Bb + k0 + 64;
        ra0 = ld8f(An);
        ra1 = ld8f(An + la);
        ra2 = ld8f(An + 2 * la);
        ra3 = ld8f(An + 3 * la);
        rb0 = ld8f(Bn);
        rb1 = ld8f(Bn + la);
        rb2 = ld8f(Bn + 2 * la);
        rb3 = ld8f(Bn + 3 * la);
      }
      __syncthreads();
#pragma unroll
      for (int kk = 0; kk < 64; kk += 32) {
        bf16x8 af[4], bfr[4];
        int kl = kk + lq * 8;
#pragma unroll
        for (int i = 0; i < 4; i++) af[i] = *(const bf16x8*)&As[wm + i * 16 + lr][kl];
#pragma unroll
        for (int j = 0; j < 4; j++) bfr[j] = *(const bf16x8*)&Bs[wn + j * 16 + lr][kl];
#pragma unroll
        for (int i = 0; i < 4; i++)
#pragma unroll
          for (int j = 0; j < 4; j++)
            acc[i][j] = __builtin_amdgcn_mfma_f32_16x16x32_bf16(af[i], bfr[j], acc[i][j], 0, 0, 0);
      }
    }
#pragma unroll
    for (int i = 0; i < 4; i++) {
      int rbase = m0 + wm + i * 16 + lq * 4;
#pragma unroll
      for (int j = 0; j < 4; j++) {
        int col = n0 + wn + j * 16 + lr;
#pragma unroll
        for (int r = 0; r < 4; r++)
          Mt[(size_t)(rbase + r) * DIM + col] = f2bf(acc[i][j][r]);
      }
    }
  } else if (b < 8256) {
    // ---- cast E (R6-proven) ----
    int base = b - 64;
    if (base < 8) {
      int j = base * 1024 + tid * 4;
      *(float4*)(rsum + j) = make_float4(0.f, 0.f, 0.f, 0.f);
    }
    int i = (base * 256 + tid) * 4;
    float4 v = *(const float4*)(E + i);
    ushort4 o;
    o.x = f2bf(v.x); o.y = f2bf(v.y); o.z = f2bf(v.z); o.w = f2bf(v.w);
    *(ushort4*)(Ebf + i) = o;
  } else {
    // ---- transpose+cast Wv (R6-proven), tile overlaid on As ----
    float* tileF = (float*)As;          // [32][33]
    int rb = b - 8256;                  // [0,1024)
    int bx = rb & 31, by = rb >> 5;
    int n0 = bx * 32, k0 = by * 32;
    int tx = tid & 31, ty = tid >> 5;   // 32 x 8
    for (int r = ty; r < 32; r += 8)
      tileF[r * 33 + tx] = Wv[(size_t)(k0 + r) * DIM + n0 + tx];
    __syncthreads();
    for (int r = ty; r < 32; r += 8)
      WtV[(size_t)(n0 + r) * DIM + k0 + tx] = f2bf(tileF[tx * 33 + r]);
  }
}

__device__ __forceinline__ void gload16(const unsigned short* g, unsigned short* l) {
  __builtin_amdgcn_global_load_lds(
      (const __attribute__((address_space(1))) unsigned int*)g,
      (__attribute__((address_space(3))) unsigned int*)l, 16, 0, 0);
}

// =====================================================================
// 8-phase 256x256 GEMM core — R4-verified schedule, FROZEN.
// lda/ldb parameterized (R10-verified); MODE 0 = bf16 store,
// MODE 1 = exp/causal-mask/rowsum epilogue (R10-verified).
// =====================================================================
template <int MODE = 0>
__device__ __forceinline__ void proj8ph(
    const unsigned short* __restrict__ A, int lda,
    const unsigned short* __restrict__ Bm, int ldb,
    unsigned short* __restrict__ C, int ldc, int m0, int n0,
    unsigned short* sA, unsigned short* sB,
    float scale = 0.f, float* __restrict__ rowsum = nullptr) {
  const int tid = threadIdx.x;
  const int lane = tid & 63;
  const int wid = tid >> 6;            // 0..7
  const int wm = (wid >> 2) * 128;     // 0 / 128
  const int wn = (wid & 3) * 64;       // 0/64/128/192
  const int lr = lane & 15, lq = lane >> 4;

  unsigned short* aB = sA + (wm >> 7) * 8192 + lr * 64;
  unsigned short* bB = sB + (wn >> 7) * 8192 + ((wn & 64) + lr) * 64;
  const int sw0 = (lq ^ (lr & 7)) * 8;
  const int sw1 = ((4 + lq) ^ (lr & 7)) * 8;

  const int schunk = (tid & 7) ^ ((tid >> 3) & 7);
  const unsigned short* gA = A + (size_t)(m0 + (tid >> 3)) * lda + schunk * 8;
  const unsigned short* gB = Bm + (size_t)(n0 + (tid >> 3)) * ldb + schunk * 8;
  unsigned short* lA = sA + wid * 512;
  unsigned short* lB = sB + wid * 512;

#define STG_A(buf, T, half) do { \
    gload16(gA + (size_t)((half) * 128) * lda + (T) * 64,      lA + (buf) * 16384 + (half) * 8192); \
    gload16(gA + (size_t)((half) * 128 + 64) * lda + (T) * 64, lA + (buf) * 16384 + (half) * 8192 + 4096); } while (0)
#define STG_B(buf, T, half) do { \
    gload16(gB + (size_t)((half) * 128) * ldb + (T) * 64,      lB + (buf) * 16384 + (half) * 8192); \
    gload16(gB + (size_t)((half) * 128 + 64) * ldb + (T) * 64, lB + (buf) * 16384 + (half) * 8192 + 4096); } while (0)
#define RD_A(buf, qr) do { _Pragma("unroll") for (int i_ = 0; i_ < 4; ++i_) { \
    af[i_][0] = *(const bf16x8*)(aB + (buf) * 16384 + ((qr) * 64 + i_ * 16) * 64 + sw0); \
    af[i_][1] = *(const bf16x8*)(aB + (buf) * 16384 + ((qr) * 64 + i_ * 16) * 64 + sw1); } } while (0)
#define RD_B(buf, qc) do { _Pragma("unroll") for (int j_ = 0; j_ < 2; ++j_) { \
    bq[qc][j_][0] = *(const bf16x8*)(bB + (buf) * 16384 + ((qc) * 32 + j_ * 16) * 64 + sw0); \
    bq[qc][j_][1] = *(const bf16x8*)(bB + (buf) * 16384 + ((qc) * 32 + j_ * 16) * 64 + sw1); } } while (0)
#define MM(qr, qc) do { __builtin_amdgcn_s_setprio(1); \
    _Pragma("unroll") for (int i_ = 0; i_ < 4; ++i_) \
    _Pragma("unroll") for (int jj_ = 0; jj_ < 2; ++jj_) { \
      acc[(qr)*4+i_][(qc)*2+jj_] = __builtin_amdgcn_mfma_f32_16x16x32_bf16(af[i_][0], bq[qc][jj_][0], acc[(qr)*4+i_][(qc)*2+jj_], 0, 0, 0); \
      acc[(qr)*4+i_][(qc)*2+jj_] = __builtin_amdgcn_mfma_f32_16x16x32_bf16(af[i_][1], bq[qc][jj_][1], acc[(qr)*4+i_][(qc)*2+jj_], 0, 0, 0); } \
    __builtin_amdgcn_s_setprio(0); } while (0)
#define BAR __builtin_amdgcn_s_barrier()
#define LGKM0 do { asm volatile("s_waitcnt lgkmcnt(0)" ::: "memory"); __builtin_amdgcn_sched_barrier(0); } while (0)
#define VM4 asm volatile("s_waitcnt vmcnt(4)" ::: "memory")
#define VM0 asm volatile("s_waitcnt vmcnt(0)" ::: "memory")

  floatx4 acc[8][4] = {};
  bf16x8 af[4][2], bq[2][2][2];

  STG_B(0, 0, 0); STG_B(0, 0, 1);
  STG_A(0, 0, 0); STG_A(0, 0, 1);
  STG_B(1, 1, 0); STG_B(1, 1, 1);
  VM4;
  BAR;

#pragma unroll 1
  for (int j = 0; j < 8; ++j) {
    const int t0 = 2 * j, t1 = 2 * j + 1;
    const bool st = (j < 7);
    RD_A(0, 0); RD_B(0, 0);
    STG_A(1, t1, 0);
    BAR; LGKM0; MM(0, 0); BAR;

    RD_B(0, 1);
    STG_A(1, t1, 1);
    BAR; LGKM0; MM(0, 1); BAR;

    RD_A(0, 1);
    if (st) STG_B(0, t0 + 2, 0);
    BAR; LGKM0; MM(1, 0); BAR;

    if (st) STG_B(0, t0 + 2, 1);
    BAR; MM(1, 1);
    if (st) { VM4; } else { VM0; }
    BAR;

    RD_A(1, 0); RD_B(1, 0);
    if (st) STG_A(0, t0 + 2, 0);
    BAR; LGKM0; MM(0, 0); BAR;

    RD_B(1, 1);
    if (st) STG_A(0, t0 + 2, 1);
    BAR; LGKM0; MM(0, 1); BAR;

    RD_A(1, 1);
    if (st) STG_B(1, t1 + 2, 0);
    BAR; LGKM0; MM(1, 0); BAR;

    if (st) STG_B(1, t1 + 2, 1);
    BAR; MM(1, 1);
    if (st) { VM4; }
    BAR;
  }
#undef STG_A
#undef STG_B
#undef RD_A
#undef RD_B
#undef MM
#undef BAR
#undef LGKM0
#undef VM4
#undef VM0

  if constexpr (MODE == 1) {
    // exp numerator + causal mask + rowsum atomics on the verified C/D layout
#pragma unroll
    for (int i = 0; i < 8; ++i) {
      int rbase = m0 + wm + i * 16 + lq * 4;
      float s0 = 0.f, s1 = 0.f, s2 = 0.f, s3 = 0.f;
#pragma unroll
      for (int jc = 0; jc < 4; ++jc) {
        int col = n0 + wn + jc * 16 + lr;
        float e0 = (col <= rbase + 0) ? __expf(acc[i][jc][0] * scale) : 0.0f;
        float e1 = (col <= rbase + 1) ? __expf(acc[i][jc][1] * scale) : 0.0f;
        float e2 = (col <= rbase + 2) ? __expf(acc[i][jc][2] * scale) : 0.0f;
        float e3 = (col <= rbase + 3) ? __expf(acc[i][jc][3] * scale) : 0.0f;
        C[(size_t)(rbase + 0) * ldc + col] = f2bf(e0);
        C[(size_t)(rbase + 1) * ldc + col] = f2bf(e1);
        C[(size_t)(rbase + 2) * ldc + col] = f2bf(e2);
        C[(size_t)(rbase + 3) * ldc + col] = f2bf(e3);
        s0 += e0; s1 += e1; s2 += e2; s3 += e3;
      }
#pragma unroll
      for (int m = 1; m < 16; m <<= 1) {
        s0 += __shfl_xor(s0, m, 64);
        s1 += __shfl_xor(s1, m, 64);
        s2 += __shfl_xor(s2, m, 64);
        s3 += __shfl_xor(s3, m, 64);
      }
      if (lr == 0) {
        atomicAdd(&rowsum[rbase + 0], s0);
        atomicAdd(&rowsum[rbase + 1], s1);
        atomicAdd(&rowsum[rbase + 2], s2);
        atomicAdd(&rowsum[rbase + 3], s3);
      }
    }
  } else {
#pragma unroll
    for (int i = 0; i < 8; ++i) {
      int rbase = m0 + wm + i * 16 + lq * 4;
#pragma unroll
      for (int jc = 0; jc < 4; ++jc) {
        int col = n0 + wn + jc * 16 + lr;
#pragma unroll
        for (int r = 0; r < 4; ++r)
          C[(size_t)(rbase + r) * ldc + col] = f2bf(acc[i][jc][r]);
      }
    }
  }
}

// ---------------- bulk: Vt (128 blk) + EM (128 blk), all 256² 8ph = ONE uniform round ----------------
__global__ __launch_bounds__(512, 2) void bulk8(
    const unsigned short* __restrict__ Ebf,
    const unsigned short* __restrict__ WtV,
    const unsigned short* __restrict__ Mt,
    unsigned short* __restrict__ Vt,
    unsigned short* __restrict__ EM) {
  __shared__ __align__(16) unsigned short sA[32768];  // 64 KiB
  __shared__ __align__(16) unsigned short sB[32768];  // 64 KiB
  int x = blockIdx.x;
  if (x < 128) {
    // Vt = WtV x Ebf^T : [1024][8192], 256² tiles (4 x 32)
    proj8ph<0>(WtV, DIM, Ebf, DIM, Vt, BSZ * SEQ, (x >> 5) * 256, (x & 31) * 256, sA, sB);
  } else {
    x -= 128;
    // EM = Ebf x Mt^T : [8192][1024], 256² tiles (32 x 4)
    proj8ph<0>(Ebf, DIM, Mt, DIM, EM, DIM, (x >> 2) * 256, (x & 3) * 256, sA, sB);
  }
}

// ---------------- scores (R10-verified structure): A=EM, B=Ebf, tri grid, ONE round ----------------
__global__ __launch_bounds__(512, 2) void scores256(
    const unsigned short* __restrict__ EM,
    const unsigned short* __restrict__ Ebf,
    unsigned short* __restrict__ ExpS,
    float* __restrict__ Rsum) {
  __shared__ __align__(16) unsigned short sA[32768];  // 64 KiB
  __shared__ __align__(16) unsigned short sB[32768];  // 64 KiB
  int t = blockIdx.x;                 // 0..35
  int mt = 0;
  while (((mt + 1) * (mt + 2)) / 2 <= t) mt++;
  int nt = t - (mt * (mt + 1)) / 2;
  const unsigned short* A = EM + (size_t)blockIdx.z * SEQ * DIM;
  const unsigned short* B = Ebf + (size_t)blockIdx.z * SEQ * DIM;
  proj8ph<1>(A, DIM, B, DIM,
             ExpS + (size_t)blockIdx.z * SEQ * SEQ, SEQ,
             mt * 256, nt * 256, sA, sB,
             0.03125f /* 1/sqrt(1024) */,
             Rsum + (size_t)blockIdx.z * SEQ);
}

// =====================================================================
// PV on the R2-proven ring-4 core (R5/R6-verified), 256-thread 128x128.
// MODE 2: causal Keff, complementary z-pairing. UNCHANGED from R10.
// =====================================================================
template <typename OutT, int MODE>
__global__ __launch_bounds__(256, 2) void gemm_ring(
    const unsigned short* __restrict__ A, int lda, long long strideA,
    const unsigned short* __restrict__ B, int ldb, long long strideB,
    OutT* __restrict__ C, int ldc, long long strideC,
    int Kdim, float scale, float* __restrict__ rowsum) {
  int m0, n0;
  if constexpr (MODE == 1) {
    int t = blockIdx.x;
    int mt = 0;
    while (((mt + 1) * (mt + 2)) / 2 <= t) mt++;
    int nt = t - (mt * (mt + 1)) / 2;
    m0 = mt * 128; n0 = nt * 128;
  } else {
    int yy = ((blockIdx.z >> 1) & 1) ? blockIdx.y : (gridDim.y - 1 - blockIdx.y);
    m0 = yy * 128;
    n0 = blockIdx.x * 128;
  }
  const int Keff = (MODE == 2) ? min(Kdim, m0 + 128) : Kdim;
  const int NT = Keff >> 5;
  A += (long long)blockIdx.z * strideA;
  B += (long long)blockIdx.z * strideB;
  C += (long long)blockIdx.z * strideC;
  rowsum += (size_t)blockIdx.z * SEQ;

  __shared__ __align__(16) unsigned short sA[4 * 4096];  // 32 KiB
  __shared__ __align__(16) unsigned short sB[4 * 4096];  // 32 KiB

  const int tid = threadIdx.x;
  const int lane = tid & 63;
  const int wid = tid >> 6;
  const int wm = (wid >> 1) * 64, wn = (wid & 1) * 64;
  const int lr = lane & 15, lq = lane >> 4;

  const int schunk = (tid & 3) ^ ((tid >> 3) & 3);
  const unsigned short* gA = A + (size_t)(m0 + (tid >> 2)) * lda + schunk * 8;
  const unsigned short* gB = B + (size_t)(n0 + (tid >> 2)) * ldb + schunk * 8;
  unsigned short* lA = sA + wid * 512;
  unsigned short* lB = sB + wid * 512;
  const size_t sGA = (size_t)64 * lda, sGB = (size_t)64 * ldb;

#define RSTAGE(T) do { int rb_ = (T) & 3; \
    gload16(gA + (size_t)(T) * 32,       lA + rb_ * 4096); \
    gload16(gA + (size_t)(T) * 32 + sGA, lA + rb_ * 4096 + 2048); \
    gload16(gB + (size_t)(T) * 32,       lB + rb_ * 4096); \
    gload16(gB + (size_t)(T) * 32 + sGB, lB + rb_ * 4096 + 2048); } while (0)
#define RARD(rb_, rowv) (*(const bf16x8*)&sA[(rb_) * 4096 + (rowv) * 32 + (lq ^ (((rowv) >> 1) & 3)) * 8])
#define RBRD(rb_, rowv) (*(const bf16x8*)&sB[(rb_) * 4096 + (rowv) * 32 + (lq ^ (((rowv) >> 1) & 3)) * 8])

  floatx4 acc[4][4] = {};

  RSTAGE(0); RSTAGE(1); RSTAGE(2);
  asm volatile("s_waitcnt vmcnt(8)" ::: "memory");
  __builtin_amdgcn_s_barrier();

  for (int T = 0; T < NT; ++T) {
    const int rb = T & 3;
    bf16x8 af[4], bfr[4];
#pragma unroll
    for (int j = 0; j < 4; ++j) bfr[j] = RBRD(rb, wn + j * 16 + lr);
#pragma unroll
    for (int i = 0; i < 4; ++i) af[i] = RARD(rb, wm + i * 16 + lr);
    if (T + 3 < NT) RSTAGE(T + 3);
    __builtin_amdgcn_s_barrier();
    __builtin_amdgcn_s_setprio(1);
#pragma unroll
    for (int i = 0; i < 4; ++i)
#pragma unroll
      for (int j = 0; j < 4; ++j)
        acc[i][j] = __builtin_amdgcn_mfma_f32_16x16x32_bf16(af[i], bfr[j], acc[i][j], 0, 0, 0);
    __builtin_amdgcn_s_setprio(0);
    if (T < NT - 3)       asm volatile("s_waitcnt vmcnt(8)" ::: "memory");
    else if (T == NT - 3) asm volatile("s_waitcnt vmcnt(4)" ::: "memory");
    else if (T == NT - 2) asm volatile("s_waitcnt vmcnt(0)" ::: "memory");
    __builtin_amdgcn_s_barrier();
  }
#undef RSTAGE
#undef RARD
#undef RBRD

  if constexpr (MODE == 1) {
#pragma unroll
    for (int i = 0; i < 4; i++) {
      int rbase = m0 + wm + i * 16 + lq * 4;
      float s0 = 0.f, s1 = 0.f, s2 = 0.f, s3 = 0.f;
#pragma unroll
      for (int j = 0; j < 4; j++) {
        int col = n0 + wn + j * 16 + lr;
        float e0 = (col <= rbase + 0) ? __expf(acc[i][j][0] * scale) : 0.0f;
        float e1 = (col <= rbase + 1) ? __expf(acc[i][j][1] * scale) : 0.0f;
        float e2 = (col <= rbase + 2) ? __expf(acc[i][j][2] * scale) : 0.0f;
        float e3 = (col <= rbase + 3) ? __expf(acc[i][j][3] * scale) : 0.0f;
        store_c(&C[(size_t)(rbase + 0) * ldc + col], e0);
        store_c(&C[(size_t)(rbase + 1) * ldc + col], e1);
        store_c(&C[(size_t)(rbase + 2) * ldc + col], e2);
        store_c(&C[(size_t)(rbase + 3) * ldc + col], e3);
        s0 += e0; s1 += e1; s2 += e2; s3 += e3;
      }
#pragma unroll
      for (int m = 1; m < 16; m <<= 1) {
        s0 += __shfl_xor(s0, m, 64);
        s1 += __shfl_xor(s1, m, 64);
        s2 += __shfl_xor(s2, m, 64);
        s3 += __shfl_xor(s3, m, 64);
      }
      if (lr == 0) {
        atomicAdd(&rowsum[rbase + 0], s0);
        atomicAdd(&rowsum[rbase + 1], s1);
        atomicAdd(&rowsum[rbase + 2], s2);
        atomicAdd(&rowsum[rbase + 3], s3);
      }
    }
  } else {
#pragma unroll
    for (int i = 0; i < 4; i++) {
      int rbase = m0 + wm + i * 16 + lq * 4;
      float i0 = 1.0f / rowsum[rbase + 0];
      float i1 = 1.0f / rowsum[rbase + 1];
      float i2 = 1.0f / rowsum[rbase + 2];
      float i3 = 1.0f / rowsum[rbase + 3];
#pragma unroll
      for (int j = 0; j < 4; j++) {
        int col = n0 + wn + j * 16 + lr;
        store_c(&C[(size_t)(rbase + 0) * ldc + col], acc[i][j][0] * i0);
        store_c(&C[(size_t)(rbase + 1) * ldc + col], acc[i][j][1] * i1);
        store_c(&C[(size_t)(rbase + 2) * ldc + col], acc[i][j][2] * i2);
        store_c(&C[(size_t)(rbase + 3) * ldc + col], acc[i][j][3] * i3);
      }
    }
  }
}

extern "C" void kernel_launch(void* const* d_in, const int* in_sizes, int n_in,
                              void* d_out, int out_size, void* d_ws, size_t ws_size,
                              hipStream_t stream) {
  const float* E  = (const float*)d_in[0];
  const float* Wq = (const float*)d_in[1];
  const float* Wk = (const float*)d_in[2];
  const float* Wv = (const float*)d_in[3];
  float* out = (float*)d_out;

  char* ws = (char*)d_ws;
  size_t off = 0;
  auto alloc = [&](size_t bytes) {
    void* p = ws + off;
    off += (bytes + 255) & ~(size_t)255;
    return p;
  };
  const size_t M_ALL = (size_t)BSZ * SEQ;
  unsigned short* Ebf  = (unsigned short*)alloc(M_ALL * DIM * 2);
  unsigned short* WtV  = (unsigned short*)alloc((size_t)DIM * DIM * 2);
  unsigned short* Mt   = (unsigned short*)alloc((size_t)DIM * DIM * 2);
  unsigned short* EM   = (unsigned short*)alloc(M_ALL * DIM * 2);
  unsigned short* Vt   = (unsigned short*)alloc((size_t)DIM * M_ALL * 2);
  unsigned short* ExpS = (unsigned short*)alloc((size_t)BSZ * SEQ * SEQ * 2);
  float*          Rsum = (float*)alloc((size_t)BSZ * SEQ * 4);

  // Mt (64 MFMA blocks, grid-first, co-resident) + cast E + Wv transpose + Rsum zero
  prep<<<dim3(9280), dim3(256), 0, stream>>>(E, Wq, Wk, Wv, Ebf, WtV, Mt, Rsum);

  // Vt (128) + EM (128): ONE uniform 8ph round on 256 CUs
  bulk8<<<dim3(256), dim3(512), 0, stream>>>(Ebf, WtV, Mt, Vt, EM);

  // scores = EM x Ebf^T -> exp numerators + rowsum atomics; tri grid, ONE round
  scores256<<<dim3(36, 1, BSZ), dim3(512), 0, stream>>>(EM, Ebf, ExpS, Rsum);

  // PV: out[q][d] = (sum_k expS[q][k] * Vt[d][k]) / rowsum[q]
  gemm_ring<float, 2><<<dim3(8, 16, BSZ), dim3(256), 0, stream>>>(
      ExpS, SEQ, (long long)SEQ * SEQ,
      Vt, (int)M_ALL, (long long)SEQ,
      out, DIM, (long long)SEQ * DIM,
      SEQ, 1.0f, Rsum);
}